// Round 9
// baseline (8081.527 us; speedup 1.0000x reference)
//
#include <hip/hip_runtime.h>
#include <cstddef>
#include <cstdint>

typedef short s8v   __attribute__((ext_vector_type(8)));   // 8 x bf16 bits
typedef float f32x4 __attribute__((ext_vector_type(4)));

__device__ __forceinline__ float b2f(unsigned short u) {
  union { unsigned u; float f; } x; x.u = ((unsigned)u) << 16; return x.f;
}
__device__ __forceinline__ unsigned short f2b(float f) {
  union { float f; unsigned u; } x; x.f = f;
  unsigned u = x.u;
  return (unsigned short)((u + 0x7FFFu + ((u >> 16) & 1u)) >> 16);  // RNE
}
__device__ __forceinline__ float sigm(float x) { return 1.f / (1.f + __expf(-x)); }
__device__ __forceinline__ float tanh_(float x) { return 1.f - 2.f / (__expf(2.f * x) + 1.f); }

#define AT_LOAD(p)        __hip_atomic_load((p), __ATOMIC_RELAXED, __HIP_MEMORY_SCOPE_AGENT)
#define AT_STORE_RLX(p,v) __hip_atomic_store((p), (v), __ATOMIC_RELAXED, __HIP_MEMORY_SCOPE_AGENT)

// Cache-bypass (device-coherent) 16B load/store -> coherent L3; no fences.
__device__ __forceinline__ s8v ldg_b128_sc(const unsigned short* p) {
  s8v r;
  asm volatile("global_load_dwordx4 %0, %1, off sc0 sc1" : "=v"(r) : "v"(p) : "memory");
  return r;
}
__device__ __forceinline__ void stg_b128_sc(unsigned short* p, s8v v) {
  asm volatile("global_store_dwordx4 %0, %1, off sc0 sc1" :: "v"(p), "v"(v) : "memory");
}

// ---------------------------------------------------------------------------
// Embedding gather + f32->bf16
// ---------------------------------------------------------------------------
__global__ void __launch_bounds__(256)
k_embed(const int* __restrict__ tok, const float* __restrict__ emb,
        unsigned short* __restrict__ x1)
{
  const int g = blockIdx.x * 256 + threadIdx.x;
  if (g >= 64 * 512 * 8) return;
  const int row = g >> 3, i = g & 7;
  const int t = tok[row];
  const f32x4 v0 = *(const f32x4*)(emb + (size_t)t * 64 + i * 8);
  const f32x4 v1 = *(const f32x4*)(emb + (size_t)t * 64 + i * 8 + 4);
  s8v o;
#pragma unroll
  for (int e = 0; e < 4; ++e) { o[e] = (short)f2b(v0[e]); o[4 + e] = (short)f2b(v1[e]); }
  *(s8v*)(x1 + (size_t)row * 64 + i * 8) = o;
}

// Generic transpose+cast: dst[dir][n][k] = bf16(src[dir][k][n]); src [K][N] f32
__global__ void __launch_bounds__(256)
k_tr(const float* __restrict__ Wf, const float* __restrict__ Wb,
     unsigned short* __restrict__ out, int K, int N)
{
  __shared__ float t[64][65];
  const int tid = threadIdx.x;
  const int kt = blockIdx.x, nt = blockIdx.y, dir = blockIdx.z;
  const float* W = dir ? Wb : Wf;
#pragma unroll
  for (int i = 0; i < 16; ++i) {
    const int c = i * 256 + tid;
    const int k = c >> 6, n = c & 63;
    t[k][n] = W[(size_t)(kt * 64 + k) * N + nt * 64 + n];
  }
  __syncthreads();
#pragma unroll
  for (int i = 0; i < 16; ++i) {
    const int c = i * 256 + tid;
    const int n = c >> 6, k = c & 63;
    out[(size_t)dir * N * K + (size_t)(nt * 64 + n) * K + kt * 64 + k] = f2b(t[k][n]);
  }
}

// Key inverse norms
__global__ void __launch_bounds__(256)
k_norms(const float* __restrict__ formE, const float* __restrict__ concK,
        const float* __restrict__ stM, const float* __restrict__ ltM,
        const float* __restrict__ infM, float* __restrict__ inn)
{
  const int i = blockIdx.x * 256 + threadIdx.x;
  if (i >= 12600) return;
  const float* src; int loc;
  if (i < 1000)       { src = formE; loc = i; }
  else if (i < 2000)  { src = concK; loc = i - 1000; }
  else if (i < 2100)  { src = stM;   loc = i - 2000; }
  else if (i < 12100) { src = ltM;   loc = i - 2100; }
  else                { src = infM;  loc = i - 12100; }
  float ss = 0.f;
#pragma unroll 16
  for (int d = 0; d < 64; ++d) { const float v = src[(size_t)loc * 64 + d]; ss += v * v; }
  inn[i] = 1.f / (sqrtf(ss) + 1e-6f);
}

// ---------------------------------------------------------------------------
// Persistent BiLSTM phase kernel — lane-local gates, zero cross-wave traffic.
// 64 blocks = 2 dirs x 32 WGs x 128 thr (2 waves). Waves split BATCH (M):
// wave w owns batches w*32..w*32+31, all 64 gate cols (4 N-tiles), full K=512.
// MFMA C-layout => lane (fc,fg) holds all 4 gates for batches
// {w*32+mt*16+fg*4+v} at h-dim j0+fc -> gates/c/h fully in registers.
// h exchange: sc0sc1 bypass ld/st via coherent L3 + relaxed flags (r8 protocol).
// ---------------------------------------------------------------------------
template<int PHASE>
__global__ void __launch_bounds__(128, 1)
k_lstm(const unsigned short* __restrict__ xin,
       const unsigned short* __restrict__ z2fp, const unsigned short* __restrict__ z2bp,
       const unsigned short* __restrict__ wht,   // [dir][2048 col][512 k] bf16
       const float* __restrict__ Wxf, const float* __restrict__ Wxb,
       const float* __restrict__ bsf, const float* __restrict__ bsb,
       unsigned short* __restrict__ hbuf,        // [dir][parity][64][512] bf16
       unsigned short* __restrict__ yout,        // P1: y1; P2: x2
       int* __restrict__ flags,                  // [dir][32]
       float* __restrict__ cg,                   // [dir][64][512] f32 (phase 2)
       int s0, int s1, int CT)
{
  __shared__ __align__(16) unsigned short h_lds[64 * 512];  // 64KB, swizzled
  __shared__ __align__(16) unsigned short z_lds[64 * 72];   // 9KB (phase 2)
  __shared__ __align__(16) unsigned short hout[16 * 72];    // 2.25KB transpose

  const int tid  = threadIdx.x;
  const int w    = tid >> 6;
  const int lane = tid & 63;
  const int fc   = lane & 15, fg = lane >> 4;
  const int wg   = blockIdx.x & 31;
  const int dir  = blockIdx.x >> 5;
  const int j0   = wg * 16;

  const unsigned short* Wht = wht + (size_t)dir * 2048 * 512;
  const float* Wx = dir ? Wxb : Wxf;
  const unsigned short* Z2 = dir ? z2bp : z2fp;
  const float* BS = dir ? bsb : bsf;
  int* flg = flags + dir * 32;
  unsigned short* hb = hbuf + (size_t)dir * (2 * 64 * 512);

  float bias_reg[4];
#pragma unroll
  for (int nt = 0; nt < 4; ++nt) bias_reg[nt] = BS[nt * 512 + j0 + fc];

  float c_reg[8];
  if (PHASE == 1 || s0 == 0) {
#pragma unroll
    for (int i = 0; i < 8; ++i) c_reg[i] = 0.f;
  } else {
#pragma unroll
    for (int mt = 0; mt < 2; ++mt)
#pragma unroll
      for (int v = 0; v < 4; ++v)
        c_reg[mt * 4 + v] =
          cg[(size_t)dir * 32768 + (size_t)(w * 32 + mt * 16 + fg * 4 + v) * 512 + j0 + fc];
  }

  // Wh fragments, full K per wave (from pre-transposed Wht: contiguous 16B)
  s8v Bh[4][16];
#pragma unroll
  for (int nt = 0; nt < 4; ++nt)
#pragma unroll
    for (int kk = 0; kk < 16; ++kk)
      Bh[nt][kk] = *(const s8v*)(Wht + (size_t)(nt * 512 + j0 + fc) * 512 + kk * 32 + fg * 8);

  s8v Bx[4][2];
  if (PHASE == 1) {
#pragma unroll
    for (int nt = 0; nt < 4; ++nt)
#pragma unroll
      for (int kx = 0; kx < 2; ++kx) {
        s8v f;
#pragma unroll
        for (int i = 0; i < 8; ++i)
          f[i] = (short)f2b(Wx[(size_t)(kx * 32 + fg * 8 + i) * 2048 + nt * 512 + j0 + fc]);
        Bx[nt][kx] = f;
      }
  }

  for (int s = s0; s < s1; ++s) {
    const int t = dir ? (511 - s) : s;
    const int gb = tid >> 1, jh = tid & 1;

    // ---- h-independent loads first (fly under the spin) ----
    s8v xf[2][2];
    s8v zr[4];
    if (PHASE == 1) {
#pragma unroll
      for (int mt = 0; mt < 2; ++mt)
#pragma unroll
        for (int kx = 0; kx < 2; ++kx)
          xf[mt][kx] = *(const s8v*)(xin +
            ((size_t)(w * 32 + mt * 16 + fc) * 512 + t) * 64 + kx * 32 + fg * 8);
    } else {
      const int lt = dir ? (s1 - 1 - s) : (s - s0);
#pragma unroll
      for (int g = 0; g < 4; ++g)
        zr[g] = *(const s8v*)(Z2 + ((size_t)(gb * CT + lt)) * 2048 + g * 512 + j0 + jh * 8);
    }

    if (s > 0) {
      const int target = s;
      int spins = 0;
      for (;;) {
        int v = (lane < 32) ? AT_LOAD(&flg[lane]) : target;
        if (__all(v >= target)) break;
        if (++spins > (1 << 18)) break;      // bounded: never hang the harness
        __builtin_amdgcn_s_sleep(1);
      }
      // stage h_{s-1}: 32 bypass 16B loads/thread, 2 pipelined rounds of 16
      const unsigned short* hsrc = hb + (size_t)((s - 1) & 1) * (64 * 512);
      s8v t0[16], t1[16];
#pragma unroll
      for (int i = 0; i < 16; ++i) {
        const int c = i * 128 + tid;
        t0[i] = ldg_b128_sc(hsrc + (size_t)(c >> 6) * 512 + (c & 63) * 8);
      }
#pragma unroll
      for (int i = 0; i < 16; ++i) {
        const int c = (16 + i) * 128 + tid;
        t1[i] = ldg_b128_sc(hsrc + (size_t)(c >> 6) * 512 + (c & 63) * 8);
      }
      asm volatile("s_waitcnt vmcnt(16)" ::: "memory");
      __builtin_amdgcn_sched_barrier(0);
#pragma unroll
      for (int i = 0; i < 16; ++i) {
        const int c = i * 128 + tid;
        const int row = c >> 6, kb = c & 63;
        *(s8v*)((char*)h_lds + row * 1024 + ((kb * 16) ^ ((row & 7) << 4))) = t0[i];
      }
      asm volatile("s_waitcnt vmcnt(0)" ::: "memory");
      __builtin_amdgcn_sched_barrier(0);
#pragma unroll
      for (int i = 0; i < 16; ++i) {
        const int c = (16 + i) * 128 + tid;
        const int row = c >> 6, kb = c & 63;
        *(s8v*)((char*)h_lds + row * 1024 + ((kb * 16) ^ ((row & 7) << 4))) = t1[i];
      }
    }
    if (PHASE == 2) {
#pragma unroll
      for (int g = 0; g < 4; ++g)
        *(s8v*)(z_lds + gb * 72 + g * 16 + jh * 8) = zr[g];
    }
    __syncthreads();   // A (h_lds is cross-wave)

    f32x4 acc[2][4];
#pragma unroll
    for (int mt = 0; mt < 2; ++mt)
#pragma unroll
      for (int nt = 0; nt < 4; ++nt) acc[mt][nt] = (f32x4){0.f, 0.f, 0.f, 0.f};

    if (PHASE == 1) {
#pragma unroll
      for (int kx = 0; kx < 2; ++kx)
#pragma unroll
        for (int mt = 0; mt < 2; ++mt)
#pragma unroll
          for (int nt = 0; nt < 4; ++nt)
            acc[mt][nt] = __builtin_amdgcn_mfma_f32_16x16x32_bf16(xf[mt][kx], Bx[nt][kx], acc[mt][nt], 0, 0, 0);
    }
    if (s > 0) {
#pragma unroll
      for (int kk = 0; kk < 16; ++kk) {
        const int k2 = (kk * 32 + fg * 8) * 2;
        s8v a[2];
#pragma unroll
        for (int mt = 0; mt < 2; ++mt) {
          const int row = w * 32 + mt * 16 + fc;
          a[mt] = *(const s8v*)((char*)h_lds + row * 1024 + (k2 ^ ((row & 7) << 4)));
        }
#pragma unroll
        for (int mt = 0; mt < 2; ++mt)
#pragma unroll
          for (int nt = 0; nt < 4; ++nt)
            acc[mt][nt] = __builtin_amdgcn_mfma_f32_16x16x32_bf16(a[mt], Bh[nt][kk], acc[mt][nt], 0, 0, 0);
      }
    }

    // ---- gates: fully lane-local (no cross-wave reduction) ----
#pragma unroll
    for (int mt = 0; mt < 2; ++mt)
#pragma unroll
      for (int v = 0; v < 4; ++v) {
        const int b = w * 32 + mt * 16 + fg * 4 + v;
        float pi = acc[mt][0][v] + bias_reg[0];
        float pf = acc[mt][1][v] + bias_reg[1];
        float pg = acc[mt][2][v] + bias_reg[2];
        float po = acc[mt][3][v] + bias_reg[3];
        if (PHASE == 2) {
          pi += b2f(z_lds[b * 72 + 0 * 16 + fc]);
          pf += b2f(z_lds[b * 72 + 1 * 16 + fc]);
          pg += b2f(z_lds[b * 72 + 2 * 16 + fc]);
          po += b2f(z_lds[b * 72 + 3 * 16 + fc]);
        }
        const float c = sigm(pf) * c_reg[mt * 4 + v] + sigm(pi) * tanh_(pg);
        c_reg[mt * 4 + v] = c;
        hout[fc * 72 + b] = f2b(sigm(po) * tanh_(c));
      }
    asm volatile("s_waitcnt lgkmcnt(0)" ::: "memory");
    __builtin_amdgcn_sched_barrier(0);
    // ---- coalesced writeback (intra-wave transpose: bb=tid>>1 stays in-wave) --
    {
      const int bb = tid >> 1, hh = tid & 1;
      s8v o;
#pragma unroll
      for (int e = 0; e < 8; ++e) o[e] = (short)hout[(hh * 8 + e) * 72 + bb];
      stg_b128_sc(hb + (size_t)(s & 1) * (64 * 512) + bb * 512 + j0 + hh * 8, o);
      if (PHASE == 1) {
        *(s8v*)(yout + ((size_t)(bb * 512 + t)) * 1024 + dir * 512 + j0 + hh * 8) = o;
      } else if (s == 511) {
        *(s8v*)(yout + (size_t)bb * 1024 + dir * 512 + j0 + hh * 8) = o;
      }
    }
    if (PHASE == 2 && s == s1 - 1 && s1 < 512) {
#pragma unroll
      for (int mt = 0; mt < 2; ++mt)
#pragma unroll
        for (int v = 0; v < 4; ++v)
          cg[(size_t)dir * 32768 + (size_t)(w * 32 + mt * 16 + fg * 4 + v) * 512 + j0 + fc] =
            c_reg[mt * 4 + v];
    }
    __syncthreads();   // C: drains vmcnt -> sc stores acked at coherent point
    if (tid == 0) AT_STORE_RLX(&flg[wg], s + 1);
  }
}

// ---------------------------------------------------------------------------
// z2 chunk GEMM: (64*CT) x 2048, K=1024, 128x128 tiles
// ---------------------------------------------------------------------------
__global__ void __launch_bounds__(256)
k_zgemm(const unsigned short* __restrict__ A, const unsigned short* __restrict__ Wxt,
        unsigned short* __restrict__ Cf, unsigned short* __restrict__ Cb,
        int tb0, int tb1, int CT)
{
  __shared__ unsigned short As[128 * 64];
  __shared__ unsigned short Bs[128 * 64];
  const int tid = threadIdx.x;
  const int lane = tid & 63;
  const int w = tid >> 6;
  const int wm = w >> 1, wn = w & 1;
  const int bx = blockIdx.x, by = blockIdx.y, dz = blockIdx.z;
  const unsigned short* Bmat = Wxt + (size_t)dz * 2048 * 1024;
  unsigned short* C = dz ? Cb : Cf;
  const int tb = dz ? tb1 : tb0;
  const int fc = lane & 15, fk = (lane >> 4) << 3;

  f32x4 acc[4][4];
#pragma unroll
  for (int mt = 0; mt < 4; ++mt)
#pragma unroll
    for (int nt = 0; nt < 4; ++nt) acc[mt][nt] = (f32x4){0.f, 0.f, 0.f, 0.f};

  for (int kt = 0; kt < 16; ++kt) {
    __syncthreads();
#pragma unroll
    for (int i = 0; i < 4; ++i) {
      const int c = i * 256 + tid;
      const int row = c >> 3, kb = c & 7;
      const int m = by * 128 + row;
      const int b = m / CT, lt = m - b * CT;
      s8v v = *(const s8v*)(A + ((size_t)b * 512 + tb + lt) * 1024 + kt * 64 + kb * 8);
      *(s8v*)((char*)As + row * 128 + ((kb * 16) ^ ((row & 7) << 4))) = v;
    }
#pragma unroll
    for (int i = 0; i < 4; ++i) {
      const int c = i * 256 + tid;
      const int n = c >> 3, kb = c & 7;
      s8v v = *(const s8v*)(Bmat + (size_t)(bx * 128 + n) * 1024 + kt * 64 + kb * 8);
      *(s8v*)((char*)Bs + n * 128 + ((kb * 16) ^ ((n & 7) << 4))) = v;
    }
    __syncthreads();
#pragma unroll
    for (int kk = 0; kk < 2; ++kk) {
      const int k2 = (kk * 32 + fk) * 2;
      s8v a[4], bfr[4];
#pragma unroll
      for (int mt = 0; mt < 4; ++mt) {
        const int row = wm * 64 + mt * 16 + fc;
        a[mt] = *(const s8v*)((char*)As + row * 128 + (k2 ^ ((row & 7) << 4)));
      }
#pragma unroll
      for (int nt = 0; nt < 4; ++nt) {
        const int n = wn * 64 + nt * 16 + fc;
        bfr[nt] = *(const s8v*)((char*)Bs + n * 128 + (k2 ^ ((n & 7) << 4)));
      }
#pragma unroll
      for (int mt = 0; mt < 4; ++mt)
#pragma unroll
        for (int nt = 0; nt < 4; ++nt)
          acc[mt][nt] = __builtin_amdgcn_mfma_f32_16x16x32_bf16(a[mt], bfr[nt], acc[mt][nt], 0, 0, 0);
    }
  }
  const int r0 = (lane >> 4) << 2;
#pragma unroll
  for (int mt = 0; mt < 4; ++mt)
#pragma unroll
    for (int nt = 0; nt < 4; ++nt) {
      const size_t rowg = (size_t)(by * 128 + wm * 64 + mt * 16 + r0);
      const int colg = bx * 128 + wn * 64 + nt * 16 + fc;
#pragma unroll
      for (int r = 0; r < 4; ++r)
        C[(rowg + r) * 2048 + colg] = f2b(acc[mt][nt][r]);
    }
}

// ---------------------------------------------------------------------------
// Head part 1: S=1 attention collapses to v-proj -> Wo -> query
// ---------------------------------------------------------------------------
__global__ void __launch_bounds__(256)
k_head1(const unsigned short* __restrict__ x2,
        const float* __restrict__ Wv, const float* __restrict__ bv,
        const float* __restrict__ Wo, const float* __restrict__ bo,
        const float* __restrict__ mqW, const float* __restrict__ mqb,
        float* __restrict__ query)
{
  __shared__ float xs[1024], ys[512], x3[1024];
  __shared__ float part[4][64];
  const int b = blockIdx.x, tid = threadIdx.x;
  for (int i = tid; i < 1024; i += 256) xs[i] = b2f(x2[(size_t)b * 1024 + i]);
  __syncthreads();
  {
    const int o = tid * 2;
    float a0 = 0.f, a1 = 0.f;
#pragma unroll 8
    for (int e = 0; e < 1024; ++e) {
      const float xv = xs[e];
      a0 += xv * Wv[(size_t)e * 512 + o];
      a1 += xv * Wv[(size_t)e * 512 + o + 1];
    }
    ys[o] = a0 + bv[o];
    ys[o + 1] = a1 + bv[o + 1];
  }
  __syncthreads();
  {
    const int e0 = tid * 4;
    float a0 = 0.f, a1 = 0.f, a2 = 0.f, a3 = 0.f;
#pragma unroll 8
    for (int h = 0; h < 512; ++h) {
      const float yv = ys[h];
      a0 += yv * Wo[(size_t)h * 1024 + e0];
      a1 += yv * Wo[(size_t)h * 1024 + e0 + 1];
      a2 += yv * Wo[(size_t)h * 1024 + e0 + 2];
      a3 += yv * Wo[(size_t)h * 1024 + e0 + 3];
    }
    x3[e0] = a0 + bo[e0];
    x3[e0 + 1] = a1 + bo[e0 + 1];
    x3[e0 + 2] = a2 + bo[e0 + 2];
    x3[e0 + 3] = a3 + bo[e0 + 3];
  }
  __syncthreads();
  {
    const int o = tid & 63, kc = tid >> 6;
    float a = 0.f;
#pragma unroll 8
    for (int e = kc * 256; e < kc * 256 + 256; ++e) a += x3[e] * mqW[(size_t)e * 64 + o];
    part[kc][o] = a;
  }
  __syncthreads();
  if (tid < 64)
    query[b * 64 + tid] = part[0][tid] + part[1][tid] + part[2][tid] + part[3][tid] + mqb[tid];
}

// ---------------------------------------------------------------------------
// Head part 2: memory retrievals + MLP + sigmoid (f32 output)
// ---------------------------------------------------------------------------
__device__ void bank_topk(const float* __restrict__ K, const float* __restrict__ V,
                          int n, const float* __restrict__ W, const float* __restrict__ inn,
                          float qinv, const float* q, float* sims, float* red, int* redi,
                          float* acc64, int tid)
{
  for (int i = tid; i < n; i += 256) {
    float s = 0.f;
#pragma unroll 16
    for (int d = 0; d < 64; ++d) s += q[d] * K[(size_t)i * 64 + d];
    s *= qinv * inn[i];
    if (W) s *= W[i];
    sims[i] = s;
  }
  __syncthreads();
  for (int it = 0; it < 5; ++it) {
    float bv = -1e30f; int bi = 1 << 30;
    for (int i = tid; i < n; i += 256) {
      const float v = sims[i];
      if (v > bv) { bv = v; bi = i; }
    }
    red[tid] = bv; redi[tid] = bi;
    __syncthreads();
    for (int st = 128; st >= 1; st >>= 1) {
      if (tid < st) {
        const float v = red[tid + st]; const int ix = redi[tid + st];
        if (v > red[tid] || (v == red[tid] && ix < redi[tid])) { red[tid] = v; redi[tid] = ix; }
      }
      __syncthreads();
    }
    const int sel = redi[0];
    if (tid < 64) acc64[tid] += V[(size_t)sel * 64 + tid];
    if (tid == 0) sims[sel] = -1e30f;
    __syncthreads();
  }
}

__global__ void __launch_bounds__(256)
k_head2(const float* __restrict__ query,
        const float* extK, const float* extV,
        const float* formE, const float* concK, const float* concV,
        const float* stM, const float* ltM, const float* ltW,
        const float* infM, const float* infW,
        const float* __restrict__ inn,
        const float* rsW, const float* rsb,
        const float* gma, const float* bta,
        const float* mea, const float* vr,
        const float* outW, const float* outb,
        const float* finW, const float* finb,
        float* __restrict__ out)
{
  __shared__ float q[64];
  __shared__ float acc64[64];
  __shared__ float sims[10000];
  __shared__ float red[256];
  __shared__ int redi[256];
  __shared__ float r1[512];
  __shared__ float o2[128];

  const int b = blockIdx.x, tid = threadIdx.x;
  if (tid < 64) q[tid] = query[b * 64 + tid];
  __syncthreads();
  red[tid] = (tid < 64) ? q[tid] * q[tid] : 0.f;
  __syncthreads();
  for (int st = 128; st >= 1; st >>= 1) { if (tid < st) red[tid] += red[tid + st]; __syncthreads(); }
  const float qinv = 1.f / (sqrtf(red[0]) + 1e-6f);
  __syncthreads();

  if (tid < 100) {
    float s = 0.f;
#pragma unroll 16
    for (int d = 0; d < 64; ++d) s += q[d] * extK[(size_t)tid * 64 + d];
    sims[tid] = s;
  }
  __syncthreads();
  red[tid] = (tid < 100) ? sims[tid] : -1e30f;
  __syncthreads();
  for (int st = 128; st >= 1; st >>= 1) { if (tid < st && red[tid + st] > red[tid]) red[tid] = red[tid + st]; __syncthreads(); }
  const float mx = red[0];
  __syncthreads();
  red[tid] = (tid < 100) ? __expf(sims[tid] - mx) : 0.f;
  __syncthreads();
  for (int st = 128; st >= 1; st >>= 1) { if (tid < st) red[tid] += red[tid + st]; __syncthreads(); }
  const float Z = red[0];
  __syncthreads();
  if (tid < 100) sims[tid] = __expf(sims[tid] - mx) / Z;
  __syncthreads();
  if (tid < 64) {
    float a = 0.f;
    for (int i = 0; i < 100; ++i) a += sims[i] * extV[(size_t)i * 64 + tid];
    acc64[tid] = a;
  }
  __syncthreads();

  bank_topk(formE, formE, 1000,  nullptr, inn + 0,     qinv, q, sims, red, redi, acc64, tid);
  bank_topk(concK, concV, 1000,  nullptr, inn + 1000,  qinv, q, sims, red, redi, acc64, tid);
  bank_topk(stM,   stM,   100,   nullptr, inn + 2000,  qinv, q, sims, red, redi, acc64, tid);
  bank_topk(ltM,   ltM,   10000, ltW,     inn + 2100,  qinv, q, sims, red, redi, acc64, tid);
  bank_topk(infM,  infM,  500,   infW,    inn + 12100, qinv, q, sims, red, redi, acc64, tid);

  if (tid < 64) acc64[tid] *= (1.f / 26.f);
  __syncthreads();

  {
    const int o = tid * 2;
    float a0 = 0.f, a1 = 0.f;
#pragma unroll 16
    for (int d = 0; d < 64; ++d) {
      const float xv = acc64[d];
      a0 += xv * rsW[(size_t)d * 512 + o];
      a1 += xv * rsW[(size_t)d * 512 + o + 1];
    }
    a0 = fmaxf(a0 + rsb[o], 0.f);
    a1 = fmaxf(a1 + rsb[o + 1], 0.f);
    r1[o]     = (a0 - mea[o])     / sqrtf(vr[o]     + 1e-3f) * gma[o]     + bta[o];
    r1[o + 1] = (a1 - mea[o + 1]) / sqrtf(vr[o + 1] + 1e-3f) * gma[o + 1] + bta[o + 1];
  }
  __syncthreads();
  if (tid < 128) {
    float a = 0.f;
#pragma unroll 8
    for (int j = 0; j < 512; ++j) a += r1[j] * outW[(size_t)j * 128 + tid];
    o2[tid] = a + outb[tid];
  }
  __syncthreads();
  red[tid] = (tid < 128) ? o2[tid] * finW[tid] : 0.f;
  __syncthreads();
  for (int st = 128; st >= 1; st >>= 1) { if (tid < st) red[tid] += red[tid + st]; __syncthreads(); }
  if (tid == 0) out[b] = sigm(red[0] + finb[0]);
}

// Diagnostic: encode ws MiB as float
__global__ void k_diag(float* out, int n, float val) {
  const int i = blockIdx.x * 64 + threadIdx.x;
  if (i < n) out[i] = val;
}

// ---------------------------------------------------------------------------
// Launch
// ---------------------------------------------------------------------------
extern "C" void kernel_launch(void* const* d_in, const int* in_sizes, int n_in,
                              void* d_out, int out_size, void* d_ws, size_t ws_size,
                              hipStream_t stream)
{
  (void)in_sizes; (void)n_in;
  const int*   tokens = (const int*)d_in[0];
  const float* emb    = (const float*)d_in[1];
  const float* l1fWx  = (const float*)d_in[2];
  const float* l1fWh  = (const float*)d_in[3];
  const float* l1fb   = (const float*)d_in[4];
  const float* l1bWx  = (const float*)d_in[5];
  const float* l1bWh  = (const float*)d_in[6];
  const float* l1bb   = (const float*)d_in[7];
  const float* l2fWx  = (const float*)d_in[8];
  const float* l2fWh  = (const float*)d_in[9];
  const float* l2fb   = (const float*)d_in[10];
  const float* l2bWx  = (const float*)d_in[11];
  const float* l2bWh  = (const float*)d_in[12];
  const float* l2bb   = (const float*)d_in[13];
  const float* Wv     = (const float*)d_in[18];
  const float* bv     = (const float*)d_in[19];
  const float* Wo     = (const float*)d_in[20];
  const float* bo     = (const float*)d_in[21];
  const float* mqW    = (const float*)d_in[22];
  const float* mqb    = (const float*)d_in[23];
  const float* extK   = (const float*)d_in[24];
  const float* extV   = (const float*)d_in[25];
  const float* formE  = (const float*)d_in[26];
  const float* concK  = (const float*)d_in[27];
  const float* concV  = (const float*)d_in[28];
  const float* stM    = (const float*)d_in[29];
  const float* ltM    = (const float*)d_in[30];
  const float* ltW    = (const float*)d_in[31];
  const float* infM   = (const float*)d_in[32];
  const float* infW   = (const float*)d_in[33];
  const float* rsW    = (const float*)d_in[34];
  const float* rsb    = (const float*)d_in[35];
  const float* gma    = (const float*)d_in[36];
  const float* bta    = (const float*)d_in[37];
  const float* mea    = (const float*)d_in[38];
  const float* vr     = (const float*)d_in[39];
  const float* outW   = (const float*)d_in[40];
  const float* outb   = (const float*)d_in[41];
  const float* finW   = (const float*)d_in[42];
  const float* finb   = (const float*)d_in[43];

  float* outp = (float*)d_out;
  char* ws = (char*)d_ws;

  size_t off = 0;
  auto take = [&](size_t sz) { size_t o = off; off += (sz + 255) & ~(size_t)255; return o; };
  const size_t o_x1    = take((size_t)64 * 512 * 64 * 2);
  const size_t o_y1    = take((size_t)64 * 512 * 1024 * 2);
  const size_t o_wxt   = take((size_t)2 * 2048 * 1024 * 2);
  const size_t o_wht1  = take((size_t)2 * 2048 * 512 * 2);
  const size_t o_wht2  = take((size_t)2 * 2048 * 512 * 2);
  const size_t o_h1    = take((size_t)2 * 2 * 64 * 512 * 2);
  const size_t o_h2    = take((size_t)2 * 2 * 64 * 512 * 2);
  const size_t o_cg    = take((size_t)2 * 64 * 512 * 4);
  const size_t o_x2    = take((size_t)64 * 1024 * 2);
  const size_t o_query = take((size_t)64 * 64 * 4);
  const size_t o_norms = take((size_t)12600 * 4);
  const size_t o_flags = take(512);
  const size_t base = off;

  int CT = 0;
  const int cts[6] = {512, 256, 128, 64, 32, 16};
  for (int i = 0; i < 6; ++i) {
    const size_t need = base + (size_t)cts[i] * 524288 + 256;
    if (need <= ws_size) { CT = cts[i]; break; }
  }
  if (CT == 0) {
    k_diag<<<1, 64, 0, stream>>>(outp, out_size, (float)(ws_size >> 20));
    return;
  }
  const size_t o_zc = take((size_t)CT * 524288);

  unsigned short* x1   = (unsigned short*)(ws + o_x1);
  unsigned short* y1   = (unsigned short*)(ws + o_y1);
  unsigned short* wxt  = (unsigned short*)(ws + o_wxt);
  unsigned short* wht1 = (unsigned short*)(ws + o_wht1);
  unsigned short* wht2 = (unsigned short*)(ws + o_wht2);
  unsigned short* h1   = (unsigned short*)(ws + o_h1);
  unsigned short* h2   = (unsigned short*)(ws + o_h2);
  float*          cg   = (float*)(ws + o_cg);
  unsigned short* x2   = (unsigned short*)(ws + o_x2);
  float*          qry  = (float*)(ws + o_query);
  float*          nrm  = (float*)(ws + o_norms);
  int*            flags = (int*)(ws + o_flags);
  unsigned short* zcf  = (unsigned short*)(ws + o_zc);
  unsigned short* zcb  = zcf + (size_t)64 * CT * 2048;

  hipMemsetAsync(flags, 0, 512, stream);
  k_embed<<<1024, 256, 0, stream>>>(tokens, emb, x1);
  k_norms<<<50, 256, 0, stream>>>(formE, concK, stM, ltM, infM, nrm);
  k_tr<<<dim3(8, 32, 2), 256, 0, stream>>>(l1fWh, l1bWh, wht1, 512, 2048);
  k_tr<<<dim3(8, 32, 2), 256, 0, stream>>>(l2fWh, l2bWh, wht2, 512, 2048);
  k_tr<<<dim3(16, 32, 2), 256, 0, stream>>>(l2fWx, l2bWx, wxt, 1024, 2048);

  k_lstm<1><<<64, 128, 0, stream>>>(x1, nullptr, nullptr, wht1, l1fWx, l1bWx,
                                    l1fb, l1bb, h1, y1, flags, nullptr, 0, 512, 512);

  const int nC = 512 / CT;
  for (int c = 0; c < nC; ++c) {
    const int s0 = c * CT, s1 = s0 + CT;
    k_zgemm<<<dim3(16, (64 * CT) / 128, 2), 256, 0, stream>>>(
        y1, wxt, zcf, zcb, s0, 512 - s1, CT);
    k_lstm<2><<<64, 128, 0, stream>>>(nullptr, zcf, zcb, wht2, nullptr, nullptr,
                                      l2fb, l2bb, h2, x2, flags + 64, cg, s0, s1, CT);
  }

  k_head1<<<64, 256, 0, stream>>>(x2, Wv, bv, Wo, bo, mqW, mqb, qry);
  k_head2<<<64, 256, 0, stream>>>(qry, extK, extV, formE, concK, concV, stM, ltM, ltW,
                                  infM, infW, nrm, rsW, rsb, gma, bta, mea, vr,
                                  outW, outb, finW, finb, outp);
}

// Round 10
// 5995.702 us; speedup vs baseline: 1.3479x; 1.3479x over previous
//
#include <hip/hip_runtime.h>
#include <cstddef>
#include <cstdint>

typedef short s8v   __attribute__((ext_vector_type(8)));   // 8 x bf16 bits
typedef float f32x4 __attribute__((ext_vector_type(4)));

__device__ __forceinline__ float b2f(unsigned short u) {
  union { unsigned u; float f; } x; x.u = ((unsigned)u) << 16; return x.f;
}
__device__ __forceinline__ unsigned short f2b(float f) {
  union { float f; unsigned u; } x; x.f = f;
  unsigned u = x.u;
  return (unsigned short)((u + 0x7FFFu + ((u >> 16) & 1u)) >> 16);  // RNE
}
__device__ __forceinline__ float sigm(float x) { return 1.f / (1.f + __expf(-x)); }
__device__ __forceinline__ float tanh_(float x) { return 1.f - 2.f / (__expf(2.f * x) + 1.f); }

#define AT_LOAD(p)        __hip_atomic_load((p), __ATOMIC_RELAXED, __HIP_MEMORY_SCOPE_AGENT)
#define AT_STORE_RLX(p,v) __hip_atomic_store((p), (v), __ATOMIC_RELAXED, __HIP_MEMORY_SCOPE_AGENT)

// Cache-bypass (device-coherent) 16B load/store -> coherent L3; no fences.
__device__ __forceinline__ s8v ldg_b128_sc(const unsigned short* p) {
  s8v r;
  asm volatile("global_load_dwordx4 %0, %1, off sc0 sc1" : "=v"(r) : "v"(p) : "memory");
  return r;
}
__device__ __forceinline__ void stg_b128_sc(unsigned short* p, s8v v) {
  asm volatile("global_store_dwordx4 %0, %1, off sc0 sc1" :: "v"(p), "v"(v) : "memory");
}

// ---------------------------------------------------------------------------
// Embedding gather + f32->bf16, emits x1t[t][b][e] (time-major for lstm reads)
// ---------------------------------------------------------------------------
__global__ void __launch_bounds__(256)
k_embed(const int* __restrict__ tok, const float* __restrict__ emb,
        unsigned short* __restrict__ x1t)
{
  const int g = blockIdx.x * 256 + threadIdx.x;
  if (g >= 64 * 512 * 8) return;
  const int row = g >> 3, i = g & 7;          // row = b*512 + t
  const int b = row >> 9, t = row & 511;
  const int tk = tok[row];
  const f32x4 v0 = *(const f32x4*)(emb + (size_t)tk * 64 + i * 8);
  const f32x4 v1 = *(const f32x4*)(emb + (size_t)tk * 64 + i * 8 + 4);
  s8v o;
#pragma unroll
  for (int e = 0; e < 4; ++e) { o[e] = (short)f2b(v0[e]); o[4 + e] = (short)f2b(v1[e]); }
  *(s8v*)(x1t + ((size_t)t * 64 + b) * 64 + i * 8) = o;
}

// Generic transpose+cast: dst[dir][n][k] = bf16(src[dir][k][n]); src [K][N] f32
__global__ void __launch_bounds__(256)
k_tr(const float* __restrict__ Wf, const float* __restrict__ Wb,
     unsigned short* __restrict__ out, int K, int N)
{
  __shared__ float t[64][65];
  const int tid = threadIdx.x;
  const int kt = blockIdx.x, nt = blockIdx.y, dir = blockIdx.z;
  const float* W = dir ? Wb : Wf;
#pragma unroll
  for (int i = 0; i < 16; ++i) {
    const int c = i * 256 + tid;
    const int k = c >> 6, n = c & 63;
    t[k][n] = W[(size_t)(kt * 64 + k) * N + nt * 64 + n];
  }
  __syncthreads();
#pragma unroll
  for (int i = 0; i < 16; ++i) {
    const int c = i * 256 + tid;
    const int n = c >> 6, k = c & 63;
    out[(size_t)dir * N * K + (size_t)(nt * 64 + n) * K + kt * 64 + k] = f2b(t[k][n]);
  }
}

// Key inverse norms
__global__ void __launch_bounds__(256)
k_norms(const float* __restrict__ formE, const float* __restrict__ concK,
        const float* __restrict__ stM, const float* __restrict__ ltM,
        const float* __restrict__ infM, float* __restrict__ inn)
{
  const int i = blockIdx.x * 256 + threadIdx.x;
  if (i >= 12600) return;
  const float* src; int loc;
  if (i < 1000)       { src = formE; loc = i; }
  else if (i < 2000)  { src = concK; loc = i - 1000; }
  else if (i < 2100)  { src = stM;   loc = i - 2000; }
  else if (i < 12100) { src = ltM;   loc = i - 2100; }
  else                { src = infM;  loc = i - 12100; }
  float ss = 0.f;
#pragma unroll 16
  for (int d = 0; d < 64; ++d) { const float v = src[(size_t)loc * 64 + d]; ss += v * v; }
  inn[i] = 1.f / (sqrtf(ss) + 1e-6f);
}

// ---------------------------------------------------------------------------
// Persistent BiLSTM phase kernel — lane-local gates; Wh tile in LDS (shared by
// both waves, loaded once). Waves split BATCH: wave w owns batches w*32..+31,
// all 64 gate cols, full K=512. Lane (fc,fg) holds all 4 gates for its 8
// batches at h-dim j0+fc -> gates/c/h fully in registers.
// h exchange: sc0sc1 bypass ld/st via coherent L3 + relaxed flags.
// ---------------------------------------------------------------------------
template<int PHASE>
__global__ void __launch_bounds__(128, 1)
k_lstm(const unsigned short* __restrict__ x1t,
       const unsigned short* __restrict__ z2fp, const unsigned short* __restrict__ z2bp,
       const unsigned short* __restrict__ wht,   // [dir][2048 col][512 k] bf16
       const float* __restrict__ Wxf, const float* __restrict__ Wxb,
       const float* __restrict__ bsf, const float* __restrict__ bsb,
       unsigned short* __restrict__ hbuf,        // [dir][parity][64][512] bf16
       unsigned short* __restrict__ yout,        // P1: y1; P2: x2
       int* __restrict__ flags,                  // [dir][32]
       float* __restrict__ cg,                   // [dir][64][512] f32 (phase 2)
       int s0, int s1, int CT)
{
  __shared__ __align__(16) unsigned short h_lds[64 * 512];   // 64KB, swizzled
  __shared__ __align__(16) unsigned short wh_lds[64 * 512];  // 64KB, swizzled
  __shared__ __align__(16) unsigned short z_lds[64 * 72];    // 9KB (phase 2)
  __shared__ __align__(16) unsigned short hout[16 * 72];     // 2.25KB transpose

  const int tid  = threadIdx.x;
  const int w    = tid >> 6;
  const int lane = tid & 63;
  const int fc   = lane & 15, fg = lane >> 4;
  const int wg   = blockIdx.x & 31;
  const int dir  = blockIdx.x >> 5;
  const int j0   = wg * 16;

  const unsigned short* Wht = wht + (size_t)dir * 2048 * 512;
  const float* Wx = dir ? Wxb : Wxf;
  const unsigned short* Z2 = dir ? z2bp : z2fp;
  const float* BS = dir ? bsb : bsf;
  int* flg = flags + dir * 32;
  unsigned short* hb = hbuf + (size_t)dir * (2 * 64 * 512);

  float bias_reg[4];
#pragma unroll
  for (int nt = 0; nt < 4; ++nt) bias_reg[nt] = BS[nt * 512 + j0 + fc];

  float c_reg[8];
  if (PHASE == 1 || s0 == 0) {
#pragma unroll
    for (int i = 0; i < 8; ++i) c_reg[i] = 0.f;
  } else {
#pragma unroll
    for (int mt = 0; mt < 2; ++mt)
#pragma unroll
      for (int v = 0; v < 4; ++v)
        c_reg[mt * 4 + v] =
          cg[(size_t)dir * 32768 + (size_t)(w * 32 + mt * 16 + fg * 4 + v) * 512 + j0 + fc];
  }

  // one-time: load this WG's Wh tile (64 cols x 512 k) into swizzled LDS
#pragma unroll
  for (int i = 0; i < 32; ++i) {
    const int c = i * 128 + tid;
    const int lc = c >> 6, kq8 = c & 63;        // local col, k-chunk of 8
    const int nt = lc >> 4, fcc = lc & 15;
    s8v v = *(const s8v*)(Wht + (size_t)(nt * 512 + j0 + fcc) * 512 + kq8 * 8);
    *(s8v*)((char*)wh_lds + lc * 1024 + ((kq8 * 16) ^ ((lc & 7) << 4))) = v;
  }

  s8v Bx[4][2];
  if (PHASE == 1) {
#pragma unroll
    for (int nt = 0; nt < 4; ++nt)
#pragma unroll
      for (int kx = 0; kx < 2; ++kx) {
        s8v f;
#pragma unroll
        for (int i = 0; i < 8; ++i)
          f[i] = (short)f2b(Wx[(size_t)(kx * 32 + fg * 8 + i) * 2048 + nt * 512 + j0 + fc]);
        Bx[nt][kx] = f;
      }
  }
  __syncthreads();   // wh_lds ready

  for (int s = s0; s < s1; ++s) {
    const int t = dir ? (511 - s) : s;
    const int gb = tid >> 1, jh = tid & 1;

    // ---- h-independent loads first (fly under the spin) ----
    s8v xf[2][2];
    s8v zr[4];
    if (PHASE == 1) {
#pragma unroll
      for (int mt = 0; mt < 2; ++mt)
#pragma unroll
        for (int kx = 0; kx < 2; ++kx)
          xf[mt][kx] = *(const s8v*)(x1t +
            ((size_t)t * 64 + (w * 32 + mt * 16 + fc)) * 64 + kx * 32 + fg * 8);
    } else {
      const int lt = dir ? (s1 - 1 - s) : (s - s0);
#pragma unroll
      for (int g = 0; g < 4; ++g)
        zr[g] = *(const s8v*)(Z2 + ((size_t)(gb * CT + lt)) * 2048 + g * 512 + j0 + jh * 8);
    }

    if (s > 0) {
      const int target = s;
      int spins = 0;
      for (;;) {
        int v = (lane < 32) ? AT_LOAD(&flg[lane]) : target;
        if (__all(v >= target)) break;
        if (++spins > (1 << 18)) break;      // bounded: never hang the harness
        __builtin_amdgcn_s_sleep(1);
      }
      // stage h_{s-1}: 32 bypass 16B loads/thread, 2 pipelined rounds of 16
      const unsigned short* hsrc = hb + (size_t)((s - 1) & 1) * (64 * 512);
      s8v t0[16], t1[16];
#pragma unroll
      for (int i = 0; i < 16; ++i) {
        const int c = i * 128 + tid;
        t0[i] = ldg_b128_sc(hsrc + (size_t)(c >> 6) * 512 + (c & 63) * 8);
      }
#pragma unroll
      for (int i = 0; i < 16; ++i) {
        const int c = (16 + i) * 128 + tid;
        t1[i] = ldg_b128_sc(hsrc + (size_t)(c >> 6) * 512 + (c & 63) * 8);
      }
      asm volatile("s_waitcnt vmcnt(16)" ::: "memory");
      __builtin_amdgcn_sched_barrier(0);
#pragma unroll
      for (int i = 0; i < 16; ++i) {
        const int c = i * 128 + tid;
        const int row = c >> 6, kb = c & 63;
        *(s8v*)((char*)h_lds + row * 1024 + ((kb * 16) ^ ((row & 7) << 4))) = t0[i];
      }
      asm volatile("s_waitcnt vmcnt(0)" ::: "memory");
      __builtin_amdgcn_sched_barrier(0);
#pragma unroll
      for (int i = 0; i < 16; ++i) {
        const int c = (16 + i) * 128 + tid;
        const int row = c >> 6, kb = c & 63;
        *(s8v*)((char*)h_lds + row * 1024 + ((kb * 16) ^ ((row & 7) << 4))) = t1[i];
      }
    }
    if (PHASE == 2) {
#pragma unroll
      for (int g = 0; g < 4; ++g)
        *(s8v*)(z_lds + gb * 72 + g * 16 + jh * 8) = zr[g];
    }
    __syncthreads();   // A (h_lds is cross-wave)

    f32x4 acc[2][4];
#pragma unroll
    for (int mt = 0; mt < 2; ++mt)
#pragma unroll
      for (int nt = 0; nt < 4; ++nt) acc[mt][nt] = (f32x4){0.f, 0.f, 0.f, 0.f};

    if (PHASE == 1) {
#pragma unroll
      for (int kx = 0; kx < 2; ++kx)
#pragma unroll
        for (int mt = 0; mt < 2; ++mt)
#pragma unroll
          for (int nt = 0; nt < 4; ++nt)
            acc[mt][nt] = __builtin_amdgcn_mfma_f32_16x16x32_bf16(xf[mt][kx], Bx[nt][kx], acc[mt][nt], 0, 0, 0);
    }
    if (s > 0) {
#pragma unroll
      for (int kk = 0; kk < 16; ++kk) {
        const int k2 = (kk * 32 + fg * 8) * 2;
        s8v a[2], bh[4];
#pragma unroll
        for (int mt = 0; mt < 2; ++mt) {
          const int row = w * 32 + mt * 16 + fc;
          a[mt] = *(const s8v*)((char*)h_lds + row * 1024 + (k2 ^ ((row & 7) << 4)));
        }
#pragma unroll
        for (int nt = 0; nt < 4; ++nt) {
          const int lc = nt * 16 + fc;
          bh[nt] = *(const s8v*)((char*)wh_lds + lc * 1024 + (k2 ^ ((lc & 7) << 4)));
        }
#pragma unroll
        for (int mt = 0; mt < 2; ++mt)
#pragma unroll
          for (int nt = 0; nt < 4; ++nt)
            acc[mt][nt] = __builtin_amdgcn_mfma_f32_16x16x32_bf16(a[mt], bh[nt], acc[mt][nt], 0, 0, 0);
      }
    }

    // ---- gates: fully lane-local ----
#pragma unroll
    for (int mt = 0; mt < 2; ++mt)
#pragma unroll
      for (int v = 0; v < 4; ++v) {
        const int b = w * 32 + mt * 16 + fg * 4 + v;
        float pi = acc[mt][0][v] + bias_reg[0];
        float pf = acc[mt][1][v] + bias_reg[1];
        float pg = acc[mt][2][v] + bias_reg[2];
        float po = acc[mt][3][v] + bias_reg[3];
        if (PHASE == 2) {
          pi += b2f(z_lds[b * 72 + 0 * 16 + fc]);
          pf += b2f(z_lds[b * 72 + 1 * 16 + fc]);
          pg += b2f(z_lds[b * 72 + 2 * 16 + fc]);
          po += b2f(z_lds[b * 72 + 3 * 16 + fc]);
        }
        const float c = sigm(pf) * c_reg[mt * 4 + v] + sigm(pi) * tanh_(pg);
        c_reg[mt * 4 + v] = c;
        hout[fc * 72 + b] = f2b(sigm(po) * tanh_(c));
      }
    asm volatile("s_waitcnt lgkmcnt(0)" ::: "memory");
    __builtin_amdgcn_sched_barrier(0);
    // ---- coalesced writeback (intra-wave transpose) ----
    {
      const int bb = tid >> 1, hh = tid & 1;
      s8v o;
#pragma unroll
      for (int e = 0; e < 8; ++e) o[e] = (short)hout[(hh * 8 + e) * 72 + bb];
      stg_b128_sc(hb + (size_t)(s & 1) * (64 * 512) + bb * 512 + j0 + hh * 8, o);
      if (PHASE == 1) {
        *(s8v*)(yout + ((size_t)(bb * 512 + t)) * 1024 + dir * 512 + j0 + hh * 8) = o;
      } else if (s == 511) {
        *(s8v*)(yout + (size_t)bb * 1024 + dir * 512 + j0 + hh * 8) = o;
      }
    }
    if (PHASE == 2 && s == s1 - 1 && s1 < 512) {
#pragma unroll
      for (int mt = 0; mt < 2; ++mt)
#pragma unroll
        for (int v = 0; v < 4; ++v)
          cg[(size_t)dir * 32768 + (size_t)(w * 32 + mt * 16 + fg * 4 + v) * 512 + j0 + fc] =
            c_reg[mt * 4 + v];
    }
    __syncthreads();   // C: drains vmcnt -> sc stores acked at coherent point
    if (tid == 0) AT_STORE_RLX(&flg[wg], s + 1);
  }
}

// ---------------------------------------------------------------------------
// z2 chunk GEMM: (64*CT) x 2048, K=1024, 128x128 tiles
// ---------------------------------------------------------------------------
__global__ void __launch_bounds__(256)
k_zgemm(const unsigned short* __restrict__ A, const unsigned short* __restrict__ Wxt,
        unsigned short* __restrict__ Cf, unsigned short* __restrict__ Cb,
        int tb0, int tb1, int CT)
{
  __shared__ unsigned short As[128 * 64];
  __shared__ unsigned short Bs[128 * 64];
  const int tid = threadIdx.x;
  const int lane = tid & 63;
  const int w = tid >> 6;
  const int wm = w >> 1, wn = w & 1;
  const int bx = blockIdx.x, by = blockIdx.y, dz = blockIdx.z;
  const unsigned short* Bmat = Wxt + (size_t)dz * 2048 * 1024;
  unsigned short* C = dz ? Cb : Cf;
  const int tb = dz ? tb1 : tb0;
  const int fc = lane & 15, fk = (lane >> 4) << 3;

  f32x4 acc[4][4];
#pragma unroll
  for (int mt = 0; mt < 4; ++mt)
#pragma unroll
    for (int nt = 0; nt < 4; ++nt) acc[mt][nt] = (f32x4){0.f, 0.f, 0.f, 0.f};

  for (int kt = 0; kt < 16; ++kt) {
    __syncthreads();
#pragma unroll
    for (int i = 0; i < 4; ++i) {
      const int c = i * 256 + tid;
      const int row = c >> 3, kb = c & 7;
      const int m = by * 128 + row;
      const int b = m / CT, lt = m - b * CT;
      s8v v = *(const s8v*)(A + ((size_t)b * 512 + tb + lt) * 1024 + kt * 64 + kb * 8);
      *(s8v*)((char*)As + row * 128 + ((kb * 16) ^ ((row & 7) << 4))) = v;
    }
#pragma unroll
    for (int i = 0; i < 4; ++i) {
      const int c = i * 256 + tid;
      const int n = c >> 3, kb = c & 7;
      s8v v = *(const s8v*)(Bmat + (size_t)(bx * 128 + n) * 1024 + kt * 64 + kb * 8);
      *(s8v*)((char*)Bs + n * 128 + ((kb * 16) ^ ((n & 7) << 4))) = v;
    }
    __syncthreads();
#pragma unroll
    for (int kk = 0; kk < 2; ++kk) {
      const int k2 = (kk * 32 + fk) * 2;
      s8v a[4], bfr[4];
#pragma unroll
      for (int mt = 0; mt < 4; ++mt) {
        const int row = wm * 64 + mt * 16 + fc;
        a[mt] = *(const s8v*)((char*)As + row * 128 + (k2 ^ ((row & 7) << 4)));
      }
#pragma unroll
      for (int nt = 0; nt < 4; ++nt) {
        const int n = wn * 64 + nt * 16 + fc;
        bfr[nt] = *(const s8v*)((char*)Bs + n * 128 + (k2 ^ ((n & 7) << 4)));
      }
#pragma unroll
      for (int mt = 0; mt < 4; ++mt)
#pragma unroll
        for (int nt = 0; nt < 4; ++nt)
          acc[mt][nt] = __builtin_amdgcn_mfma_f32_16x16x32_bf16(a[mt], bfr[nt], acc[mt][nt], 0, 0, 0);
    }
  }
  const int r0 = (lane >> 4) << 2;
#pragma unroll
  for (int mt = 0; mt < 4; ++mt)
#pragma unroll
    for (int nt = 0; nt < 4; ++nt) {
      const size_t rowg = (size_t)(by * 128 + wm * 64 + mt * 16 + r0);
      const int colg = bx * 128 + wn * 64 + nt * 16 + fc;
#pragma unroll
      for (int r = 0; r < 4; ++r)
        C[(rowg + r) * 2048 + colg] = f2b(acc[mt][nt][r]);
    }
}

// ---------------------------------------------------------------------------
// Head part 1: S=1 attention collapses to v-proj -> Wo -> query
// ---------------------------------------------------------------------------
__global__ void __launch_bounds__(256)
k_head1(const unsigned short* __restrict__ x2,
        const float* __restrict__ Wv, const float* __restrict__ bv,
        const float* __restrict__ Wo, const float* __restrict__ bo,
        const float* __restrict__ mqW, const float* __restrict__ mqb,
        float* __restrict__ query)
{
  __shared__ float xs[1024], ys[512], x3[1024];
  __shared__ float part[4][64];
  const int b = blockIdx.x, tid = threadIdx.x;
  for (int i = tid; i < 1024; i += 256) xs[i] = b2f(x2[(size_t)b * 1024 + i]);
  __syncthreads();
  {
    const int o = tid * 2;
    float a0 = 0.f, a1 = 0.f;
#pragma unroll 8
    for (int e = 0; e < 1024; ++e) {
      const float xv = xs[e];
      a0 += xv * Wv[(size_t)e * 512 + o];
      a1 += xv * Wv[(size_t)e * 512 + o + 1];
    }
    ys[o] = a0 + bv[o];
    ys[o + 1] = a1 + bv[o + 1];
  }
  __syncthreads();
  {
    const int e0 = tid * 4;
    float a0 = 0.f, a1 = 0.f, a2 = 0.f, a3 = 0.f;
#pragma unroll 8
    for (int h = 0; h < 512; ++h) {
      const float yv = ys[h];
      a0 += yv * Wo[(size_t)h * 1024 + e0];
      a1 += yv * Wo[(size_t)h * 1024 + e0 + 1];
      a2 += yv * Wo[(size_t)h * 1024 + e0 + 2];
      a3 += yv * Wo[(size_t)h * 1024 + e0 + 3];
    }
    x3[e0] = a0 + bo[e0];
    x3[e0 + 1] = a1 + bo[e0 + 1];
    x3[e0 + 2] = a2 + bo[e0 + 2];
    x3[e0 + 3] = a3 + bo[e0 + 3];
  }
  __syncthreads();
  {
    const int o = tid & 63, kc = tid >> 6;
    float a = 0.f;
#pragma unroll 8
    for (int e = kc * 256; e < kc * 256 + 256; ++e) a += x3[e] * mqW[(size_t)e * 64 + o];
    part[kc][o] = a;
  }
  __syncthreads();
  if (tid < 64)
    query[b * 64 + tid] = part[0][tid] + part[1][tid] + part[2][tid] + part[3][tid] + mqb[tid];
}

// ---------------------------------------------------------------------------
// Head part 2: memory retrievals + MLP + sigmoid (f32 output)
// ---------------------------------------------------------------------------
__device__ void bank_topk(const float* __restrict__ K, const float* __restrict__ V,
                          int n, const float* __restrict__ W, const float* __restrict__ inn,
                          float qinv, const float* q, float* sims, float* red, int* redi,
                          float* acc64, int tid)
{
  for (int i = tid; i < n; i += 256) {
    float s = 0.f;
#pragma unroll 16
    for (int d = 0; d < 64; ++d) s += q[d] * K[(size_t)i * 64 + d];
    s *= qinv * inn[i];
    if (W) s *= W[i];
    sims[i] = s;
  }
  __syncthreads();
  for (int it = 0; it < 5; ++it) {
    float bv = -1e30f; int bi = 1 << 30;
    for (int i = tid; i < n; i += 256) {
      const float v = sims[i];
      if (v > bv) { bv = v; bi = i; }
    }
    red[tid] = bv; redi[tid] = bi;
    __syncthreads();
    for (int st = 128; st >= 1; st >>= 1) {
      if (tid < st) {
        const float v = red[tid + st]; const int ix = redi[tid + st];
        if (v > red[tid] || (v == red[tid] && ix < redi[tid])) { red[tid] = v; redi[tid] = ix; }
      }
      __syncthreads();
    }
    const int sel = redi[0];
    if (tid < 64) acc64[tid] += V[(size_t)sel * 64 + tid];
    if (tid == 0) sims[sel] = -1e30f;
    __syncthreads();
  }
}

__global__ void __launch_bounds__(256)
k_head2(const float* __restrict__ query,
        const float* extK, const float* extV,
        const float* formE, const float* concK, const float* concV,
        const float* stM, const float* ltM, const float* ltW,
        const float* infM, const float* infW,
        const float* __restrict__ inn,
        const float* rsW, const float* rsb,
        const float* gma, const float* bta,
        const float* mea, const float* vr,
        const float* outW, const float* outb,
        const float* finW, const float* finb,
        float* __restrict__ out)
{
  __shared__ float q[64];
  __shared__ float acc64[64];
  __shared__ float sims[10000];
  __shared__ float red[256];
  __shared__ int redi[256];
  __shared__ float r1[512];
  __shared__ float o2[128];

  const int b = blockIdx.x, tid = threadIdx.x;
  if (tid < 64) q[tid] = query[b * 64 + tid];
  __syncthreads();
  red[tid] = (tid < 64) ? q[tid] * q[tid] : 0.f;
  __syncthreads();
  for (int st = 128; st >= 1; st >>= 1) { if (tid < st) red[tid] += red[tid + st]; __syncthreads(); }
  const float qinv = 1.f / (sqrtf(red[0]) + 1e-6f);
  __syncthreads();

  if (tid < 100) {
    float s = 0.f;
#pragma unroll 16
    for (int d = 0; d < 64; ++d) s += q[d] * extK[(size_t)tid * 64 + d];
    sims[tid] = s;
  }
  __syncthreads();
  red[tid] = (tid < 100) ? sims[tid] : -1e30f;
  __syncthreads();
  for (int st = 128; st >= 1; st >>= 1) { if (tid < st && red[tid + st] > red[tid]) red[tid] = red[tid + st]; __syncthreads(); }
  const float mx = red[0];
  __syncthreads();
  red[tid] = (tid < 100) ? __expf(sims[tid] - mx) : 0.f;
  __syncthreads();
  for (int st = 128; st >= 1; st >>= 1) { if (tid < st) red[tid] += red[tid + st]; __syncthreads(); }
  const float Z = red[0];
  __syncthreads();
  if (tid < 100) sims[tid] = __expf(sims[tid] - mx) / Z;
  __syncthreads();
  if (tid < 64) {
    float a = 0.f;
    for (int i = 0; i < 100; ++i) a += sims[i] * extV[(size_t)i * 64 + tid];
    acc64[tid] = a;
  }
  __syncthreads();

  bank_topk(formE, formE, 1000,  nullptr, inn + 0,     qinv, q, sims, red, redi, acc64, tid);
  bank_topk(concK, concV, 1000,  nullptr, inn + 1000,  qinv, q, sims, red, redi, acc64, tid);
  bank_topk(stM,   stM,   100,   nullptr, inn + 2000,  qinv, q, sims, red, redi, acc64, tid);
  bank_topk(ltM,   ltM,   10000, ltW,     inn + 2100,  qinv, q, sims, red, redi, acc64, tid);
  bank_topk(infM,  infM,  500,   infW,    inn + 12100, qinv, q, sims, red, redi, acc64, tid);

  if (tid < 64) acc64[tid] *= (1.f / 26.f);
  __syncthreads();

  {
    const int o = tid * 2;
    float a0 = 0.f, a1 = 0.f;
#pragma unroll 16
    for (int d = 0; d < 64; ++d) {
      const float xv = acc64[d];
      a0 += xv * rsW[(size_t)d * 512 + o];
      a1 += xv * rsW[(size_t)d * 512 + o + 1];
    }
    a0 = fmaxf(a0 + rsb[o], 0.f);
    a1 = fmaxf(a1 + rsb[o + 1], 0.f);
    r1[o]     = (a0 - mea[o])     / sqrtf(vr[o]     + 1e-3f) * gma[o]     + bta[o];
    r1[o + 1] = (a1 - mea[o + 1]) / sqrtf(vr[o + 1] + 1e-3f) * gma[o + 1] + bta[o + 1];
  }
  __syncthreads();
  if (tid < 128) {
    float a = 0.f;
#pragma unroll 8
    for (int j = 0; j < 512; ++j) a += r1[j] * outW[(size_t)j * 128 + tid];
    o2[tid] = a + outb[tid];
  }
  __syncthreads();
  red[tid] = (tid < 128) ? o2[tid] * finW[tid] : 0.f;
  __syncthreads();
  for (int st = 128; st >= 1; st >>= 1) { if (tid < st) red[tid] += red[tid + st]; __syncthreads(); }
  if (tid == 0) out[b] = sigm(red[0] + finb[0]);
}

// Diagnostic: encode ws MiB as float
__global__ void k_diag(float* out, int n, float val) {
  const int i = blockIdx.x * 64 + threadIdx.x;
  if (i < n) out[i] = val;
}

// ---------------------------------------------------------------------------
// Launch
// ---------------------------------------------------------------------------
extern "C" void kernel_launch(void* const* d_in, const int* in_sizes, int n_in,
                              void* d_out, int out_size, void* d_ws, size_t ws_size,
                              hipStream_t stream)
{
  (void)in_sizes; (void)n_in;
  const int*   tokens = (const int*)d_in[0];
  const float* emb    = (const float*)d_in[1];
  const float* l1fWx  = (const float*)d_in[2];
  const float* l1fWh  = (const float*)d_in[3];
  const float* l1fb   = (const float*)d_in[4];
  const float* l1bWx  = (const float*)d_in[5];
  const float* l1bWh  = (const float*)d_in[6];
  const float* l1bb   = (const float*)d_in[7];
  const float* l2fWx  = (const float*)d_in[8];
  const float* l2fWh  = (const float*)d_in[9];
  const float* l2fb   = (const float*)d_in[10];
  const float* l2bWx  = (const float*)d_in[11];
  const float* l2bWh  = (const float*)d_in[12];
  const float* l2bb   = (const float*)d_in[13];
  const float* Wv     = (const float*)d_in[18];
  const float* bv     = (const float*)d_in[19];
  const float* Wo     = (const float*)d_in[20];
  const float* bo     = (const float*)d_in[21];
  const float* mqW    = (const float*)d_in[22];
  const float* mqb    = (const float*)d_in[23];
  const float* extK   = (const float*)d_in[24];
  const float* extV   = (const float*)d_in[25];
  const float* formE  = (const float*)d_in[26];
  const float* concK  = (const float*)d_in[27];
  const float* concV  = (const float*)d_in[28];
  const float* stM    = (const float*)d_in[29];
  const float* ltM    = (const float*)d_in[30];
  const float* ltW    = (const float*)d_in[31];
  const float* infM   = (const float*)d_in[32];
  const float* infW   = (const float*)d_in[33];
  const float* rsW    = (const float*)d_in[34];
  const float* rsb    = (const float*)d_in[35];
  const float* gma    = (const float*)d_in[36];
  const float* bta    = (const float*)d_in[37];
  const float* mea    = (const float*)d_in[38];
  const float* vr     = (const float*)d_in[39];
  const float* outW   = (const float*)d_in[40];
  const float* outb   = (const float*)d_in[41];
  const float* finW   = (const float*)d_in[42];
  const float* finb   = (const float*)d_in[43];

  float* outp = (float*)d_out;
  char* ws = (char*)d_ws;

  size_t off = 0;
  auto take = [&](size_t sz) { size_t o = off; off += (sz + 255) & ~(size_t)255; return o; };
  const size_t o_x1    = take((size_t)64 * 512 * 64 * 2);
  const size_t o_y1    = take((size_t)64 * 512 * 1024 * 2);
  const size_t o_wxt   = take((size_t)2 * 2048 * 1024 * 2);
  const size_t o_wht1  = take((size_t)2 * 2048 * 512 * 2);
  const size_t o_wht2  = take((size_t)2 * 2048 * 512 * 2);
  const size_t o_h1    = take((size_t)2 * 2 * 64 * 512 * 2);
  const size_t o_h2    = take((size_t)2 * 2 * 64 * 512 * 2);
  const size_t o_cg    = take((size_t)2 * 64 * 512 * 4);
  const size_t o_x2    = take((size_t)64 * 1024 * 2);
  const size_t o_query = take((size_t)64 * 64 * 4);
  const size_t o_norms = take((size_t)12600 * 4);
  const size_t o_flags = take(512);
  const size_t base = off;

  int CT = 0;
  const int cts[6] = {512, 256, 128, 64, 32, 16};
  for (int i = 0; i < 6; ++i) {
    const size_t need = base + (size_t)cts[i] * 524288 + 256;
    if (need <= ws_size) { CT = cts[i]; break; }
  }
  if (CT == 0) {
    k_diag<<<1, 64, 0, stream>>>(outp, out_size, (float)(ws_size >> 20));
    return;
  }
  const size_t o_zc = take((size_t)CT * 524288);

  unsigned short* x1t  = (unsigned short*)(ws + o_x1);
  unsigned short* y1   = (unsigned short*)(ws + o_y1);
  unsigned short* wxt  = (unsigned short*)(ws + o_wxt);
  unsigned short* wht1 = (unsigned short*)(ws + o_wht1);
  unsigned short* wht2 = (unsigned short*)(ws + o_wht2);
  unsigned short* h1   = (unsigned short*)(ws + o_h1);
  unsigned short* h2   = (unsigned short*)(ws + o_h2);
  float*          cg   = (float*)(ws + o_cg);
  unsigned short* x2   = (unsigned short*)(ws + o_x2);
  float*          qry  = (float*)(ws + o_query);
  float*          nrm  = (float*)(ws + o_norms);
  int*            flags = (int*)(ws + o_flags);
  unsigned short* zcf  = (unsigned short*)(ws + o_zc);
  unsigned short* zcb  = zcf + (size_t)64 * CT * 2048;

  hipMemsetAsync(flags, 0, 512, stream);
  k_embed<<<1024, 256, 0, stream>>>(tokens, emb, x1t);
  k_norms<<<50, 256, 0, stream>>>(formE, concK, stM, ltM, infM, nrm);
  k_tr<<<dim3(8, 32, 2), 256, 0, stream>>>(l1fWh, l1bWh, wht1, 512, 2048);
  k_tr<<<dim3(8, 32, 2), 256, 0, stream>>>(l2fWh, l2bWh, wht2, 512, 2048);
  k_tr<<<dim3(16, 32, 2), 256, 0, stream>>>(l2fWx, l2bWx, wxt, 1024, 2048);

  k_lstm<1><<<64, 128, 0, stream>>>(x1t, nullptr, nullptr, wht1, l1fWx, l1bWx,
                                    l1fb, l1bb, h1, y1, flags, nullptr, 0, 512, 512);

  const int nC = 512 / CT;
  for (int c = 0; c < nC; ++c) {
    const int s0 = c * CT, s1 = s0 + CT;
    k_zgemm<<<dim3(16, (64 * CT) / 128, 2), 256, 0, stream>>>(
        y1, wxt, zcf, zcb, s0, 512 - s1, CT);
    k_lstm<2><<<64, 128, 0, stream>>>(nullptr, zcf, zcb, wht2, nullptr, nullptr,
                                      l2fb, l2bb, h2, x2, flags + 64, cg, s0, s1, CT);
  }

  k_head1<<<64, 256, 0, stream>>>(x2, Wv, bv, Wo, bo, mqW, mqb, qry);
  k_head2<<<64, 256, 0, stream>>>(qry, extK, extV, formE, concK, concV, stM, ltM, ltW,
                                  infM, infW, nrm, rsW, rsb, gma, bta, mea, vr,
                                  outW, outb, finW, finb, outp);
}

// Round 11
// 5973.569 us; speedup vs baseline: 1.3529x; 1.0037x over previous
//
#include <hip/hip_runtime.h>
#include <cstddef>
#include <cstdint>

typedef short s8v   __attribute__((ext_vector_type(8)));   // 8 x bf16 bits
typedef float f32x4 __attribute__((ext_vector_type(4)));

__device__ __forceinline__ float b2f(unsigned short u) {
  union { unsigned u; float f; } x; x.u = ((unsigned)u) << 16; return x.f;
}
__device__ __forceinline__ unsigned short f2b(float f) {
  union { float f; unsigned u; } x; x.f = f;
  unsigned u = x.u;
  return (unsigned short)((u + 0x7FFFu + ((u >> 16) & 1u)) >> 16);  // RNE
}
__device__ __forceinline__ float sigm(float x) { return 1.f / (1.f + __expf(-x)); }
__device__ __forceinline__ float tanh_(float x) { return 1.f - 2.f / (__expf(2.f * x) + 1.f); }

#define AT_LOAD(p)        __hip_atomic_load((p), __ATOMIC_RELAXED, __HIP_MEMORY_SCOPE_AGENT)
#define AT_STORE_RLX(p,v) __hip_atomic_store((p), (v), __ATOMIC_RELAXED, __HIP_MEMORY_SCOPE_AGENT)

// Cache-bypass (device-coherent) 16B load/store -> coherent L3; no fences.
__device__ __forceinline__ s8v ldg_b128_sc(const unsigned short* p) {
  s8v r;
  asm volatile("global_load_dwordx4 %0, %1, off sc0 sc1" : "=v"(r) : "v"(p) : "memory");
  return r;
}
__device__ __forceinline__ void stg_b128_sc(unsigned short* p, s8v v) {
  asm volatile("global_store_dwordx4 %0, %1, off sc0 sc1" :: "v"(p), "v"(v) : "memory");
}

// ---------------------------------------------------------------------------
// Embedding gather + f32->bf16, emits x1t[t][b][e] (time-major)
// ---------------------------------------------------------------------------
__global__ void __launch_bounds__(256)
k_embed(const int* __restrict__ tok, const float* __restrict__ emb,
        unsigned short* __restrict__ x1t)
{
  const int g = blockIdx.x * 256 + threadIdx.x;
  if (g >= 64 * 512 * 8) return;
  const int row = g >> 3, i = g & 7;          // row = b*512 + t
  const int b = row >> 9, t = row & 511;
  const int tk = tok[row];
  const f32x4 v0 = *(const f32x4*)(emb + (size_t)tk * 64 + i * 8);
  const f32x4 v1 = *(const f32x4*)(emb + (size_t)tk * 64 + i * 8 + 4);
  s8v o;
#pragma unroll
  for (int e = 0; e < 4; ++e) { o[e] = (short)f2b(v0[e]); o[4 + e] = (short)f2b(v1[e]); }
  *(s8v*)(x1t + ((size_t)t * 64 + b) * 64 + i * 8) = o;
}

// Generic transpose+cast: dst[dir][n][k] = bf16(src[dir][k][n]); src [K][N] f32
__global__ void __launch_bounds__(256)
k_tr(const float* __restrict__ Wf, const float* __restrict__ Wb,
     unsigned short* __restrict__ out, int K, int N)
{
  __shared__ float t[64][65];
  const int tid = threadIdx.x;
  const int kt = blockIdx.x, nt = blockIdx.y, dir = blockIdx.z;
  const float* W = dir ? Wb : Wf;
#pragma unroll
  for (int i = 0; i < 16; ++i) {
    const int c = i * 256 + tid;
    const int k = c >> 6, n = c & 63;
    t[k][n] = W[(size_t)(kt * 64 + k) * N + nt * 64 + n];
  }
  __syncthreads();
#pragma unroll
  for (int i = 0; i < 16; ++i) {
    const int c = i * 256 + tid;
    const int n = c >> 6, k = c & 63;
    out[(size_t)dir * N * K + (size_t)(nt * 64 + n) * K + kt * 64 + k] = f2b(t[k][n]);
  }
}

// Key inverse norms
__global__ void __launch_bounds__(256)
k_norms(const float* __restrict__ formE, const float* __restrict__ concK,
        const float* __restrict__ stM, const float* __restrict__ ltM,
        const float* __restrict__ infM, float* __restrict__ inn)
{
  const int i = blockIdx.x * 256 + threadIdx.x;
  if (i >= 12600) return;
  const float* src; int loc;
  if (i < 1000)       { src = formE; loc = i; }
  else if (i < 2000)  { src = concK; loc = i - 1000; }
  else if (i < 2100)  { src = stM;   loc = i - 2000; }
  else if (i < 12100) { src = ltM;   loc = i - 2100; }
  else                { src = infM;  loc = i - 12100; }
  float ss = 0.f;
#pragma unroll 16
  for (int d = 0; d < 64; ++d) { const float v = src[(size_t)loc * 64 + d]; ss += v * v; }
  inn[i] = 1.f / (sqrtf(ss) + 1e-6f);
}

// ---------------------------------------------------------------------------
// Persistent BiLSTM phase kernel — barrier-free steady state.
// h exchanged in TRANSPOSED layout hT[parity][kchunk 0..63][batch 0..63][8]:
// consumer lanes load their MFMA A-fragments DIRECTLY to registers (no LDS).
// Flags are per-WAVE (64/dir): vmcnt is a per-wave counter, so each wave
// drains its own sc-stores and publishes independently -> no __syncthreads
// in the loop. All per-step LDS (z_lds, hout) is wave-partitioned.
// ---------------------------------------------------------------------------
template<int PHASE>
__global__ void __launch_bounds__(128, 1)
k_lstm(const unsigned short* __restrict__ x1t,
       const unsigned short* __restrict__ z2fp, const unsigned short* __restrict__ z2bp,
       const unsigned short* __restrict__ wht,   // [dir][2048 col][512 k] bf16
       const float* __restrict__ Wxf, const float* __restrict__ Wxb,
       const float* __restrict__ bsf, const float* __restrict__ bsb,
       unsigned short* __restrict__ hbuf,        // [dir][parity][64][64][8] bf16 (hT)
       unsigned short* __restrict__ yout,        // P1: y1; P2: x2
       int* __restrict__ flags,                  // [dir][64] per-wave
       float* __restrict__ cg,                   // [dir][64][512] f32 (phase 2)
       int s0, int s1, int CT)
{
  __shared__ __align__(16) unsigned short wh_lds[64 * 512];  // 64KB, swizzled
  __shared__ __align__(16) unsigned short z_lds[64 * 72];    // 9KB (phase 2)
  __shared__ __align__(16) unsigned short hout[16 * 72];     // 2.25KB transpose

  const int tid  = threadIdx.x;
  const int w    = tid >> 6;
  const int lane = tid & 63;
  const int fc   = lane & 15, fg = lane >> 4;
  const int wg   = blockIdx.x & 31;
  const int dir  = blockIdx.x >> 5;
  const int j0   = wg * 16;

  const unsigned short* Wht = wht + (size_t)dir * 2048 * 512;
  const float* Wx = dir ? Wxb : Wxf;
  const unsigned short* Z2 = dir ? z2bp : z2fp;
  const float* BS = dir ? bsb : bsf;
  int* flg = flags + dir * 64;
  unsigned short* hb = hbuf + (size_t)dir * (2 * 64 * 512);

  float bias_reg[4];
#pragma unroll
  for (int nt = 0; nt < 4; ++nt) bias_reg[nt] = BS[nt * 512 + j0 + fc];

  float c_reg[8];
  if (PHASE == 1 || s0 == 0) {
#pragma unroll
    for (int i = 0; i < 8; ++i) c_reg[i] = 0.f;
  } else {
#pragma unroll
    for (int mt = 0; mt < 2; ++mt)
#pragma unroll
      for (int v = 0; v < 4; ++v)
        c_reg[mt * 4 + v] =
          cg[(size_t)dir * 32768 + (size_t)(w * 32 + mt * 16 + fg * 4 + v) * 512 + j0 + fc];
  }

  // one-time: load this WG's Wh tile (64 cols x 512 k) into swizzled LDS
#pragma unroll
  for (int i = 0; i < 32; ++i) {
    const int c = i * 128 + tid;
    const int lc = c >> 6, kq8 = c & 63;
    const int nt = lc >> 4, fcc = lc & 15;
    s8v v = *(const s8v*)(Wht + (size_t)(nt * 512 + j0 + fcc) * 512 + kq8 * 8);
    *(s8v*)((char*)wh_lds + lc * 1024 + ((kq8 * 16) ^ ((lc & 7) << 4))) = v;
  }

  s8v Bx[4][2];
  if (PHASE == 1) {
#pragma unroll
    for (int nt = 0; nt < 4; ++nt)
#pragma unroll
      for (int kx = 0; kx < 2; ++kx) {
        s8v f;
#pragma unroll
        for (int i = 0; i < 8; ++i)
          f[i] = (short)f2b(Wx[(size_t)(kx * 32 + fg * 8 + i) * 2048 + nt * 512 + j0 + fc]);
        Bx[nt][kx] = f;
      }
  }
  __syncthreads();   // wh_lds ready (only barrier outside the loop)

  for (int s = s0; s < s1; ++s) {
    const int t = dir ? (511 - s) : s;
    const int gb = tid >> 1, jh = tid & 1;

    // ---- h-independent loads first ----
    s8v xf[2][2];
    if (PHASE == 1) {
#pragma unroll
      for (int mt = 0; mt < 2; ++mt)
#pragma unroll
        for (int kx = 0; kx < 2; ++kx)
          xf[mt][kx] = *(const s8v*)(x1t +
            ((size_t)t * 64 + (w * 32 + mt * 16 + fc)) * 64 + kx * 32 + fg * 8);
    } else {
      const int lt = dir ? (s1 - 1 - s) : (s - s0);
      s8v zr[4];
#pragma unroll
      for (int g = 0; g < 4; ++g)
        zr[g] = *(const s8v*)(Z2 + ((size_t)(gb * CT + lt)) * 2048 + g * 512 + j0 + jh * 8);
#pragma unroll
      for (int g = 0; g < 4; ++g)
        *(s8v*)(z_lds + gb * 72 + g * 16 + jh * 8) = zr[g];
    }

    f32x4 acc[2][4];
#pragma unroll
    for (int mt = 0; mt < 2; ++mt)
#pragma unroll
      for (int nt = 0; nt < 4; ++nt) acc[mt][nt] = (f32x4){0.f, 0.f, 0.f, 0.f};

    if (s > 0) {
      // ---- wait for all 64 producer waves of this direction ----
      const int target = s;
      int spins = 0;
      for (;;) {
        int v = AT_LOAD(&flg[lane]);
        if (__all(v >= target)) break;
        if (++spins > (1 << 18)) break;      // bounded: never hang the harness
        __builtin_amdgcn_s_sleep(1);
      }
    }

    if (PHASE == 1) {      // Wx MFMAs first (compiler-tracked xf waits stay clean)
#pragma unroll
      for (int kx = 0; kx < 2; ++kx)
#pragma unroll
        for (int mt = 0; mt < 2; ++mt)
#pragma unroll
          for (int nt = 0; nt < 4; ++nt)
            acc[mt][nt] = __builtin_amdgcn_mfma_f32_16x16x32_bf16(xf[mt][kx], Bx[nt][kx], acc[mt][nt], 0, 0, 0);
    }

    if (s > 0) {
      // ---- direct A-fragment loads from hT (registers, no LDS) ----
      const unsigned short* hsrc = hb + (size_t)((s - 1) & 1) * (64 * 512);
      s8v af[32];
#pragma unroll
      for (int kk = 0; kk < 16; ++kk)
#pragma unroll
        for (int mt = 0; mt < 2; ++mt)
          af[kk * 2 + mt] = ldg_b128_sc(hsrc +
            (size_t)((kk * 4 + fg) * 64 + (w * 32 + mt * 16 + fc)) * 8);

      asm volatile("s_waitcnt vmcnt(16)" ::: "memory");
      __builtin_amdgcn_sched_barrier(0);
#pragma unroll
      for (int kk = 0; kk < 8; ++kk) {
        const int k2 = (kk * 32 + fg * 8) * 2;
        s8v bh[4];
#pragma unroll
        for (int nt = 0; nt < 4; ++nt) {
          const int lc = nt * 16 + fc;
          bh[nt] = *(const s8v*)((char*)wh_lds + lc * 1024 + (k2 ^ ((lc & 7) << 4)));
        }
#pragma unroll
        for (int mt = 0; mt < 2; ++mt)
#pragma unroll
          for (int nt = 0; nt < 4; ++nt)
            acc[mt][nt] = __builtin_amdgcn_mfma_f32_16x16x32_bf16(af[kk * 2 + mt], bh[nt], acc[mt][nt], 0, 0, 0);
      }
      asm volatile("s_waitcnt vmcnt(0)" ::: "memory");
      __builtin_amdgcn_sched_barrier(0);
#pragma unroll
      for (int kk = 8; kk < 16; ++kk) {
        const int k2 = (kk * 32 + fg * 8) * 2;
        s8v bh[4];
#pragma unroll
        for (int nt = 0; nt < 4; ++nt) {
          const int lc = nt * 16 + fc;
          bh[nt] = *(const s8v*)((char*)wh_lds + lc * 1024 + (k2 ^ ((lc & 7) << 4)));
        }
#pragma unroll
        for (int mt = 0; mt < 2; ++mt)
#pragma unroll
          for (int nt = 0; nt < 4; ++nt)
            acc[mt][nt] = __builtin_amdgcn_mfma_f32_16x16x32_bf16(af[kk * 2 + mt], bh[nt], acc[mt][nt], 0, 0, 0);
      }
    }

    // ---- gates: fully lane-local ----
    if (PHASE == 2) {
      asm volatile("s_waitcnt lgkmcnt(0)" ::: "memory");
      __builtin_amdgcn_sched_barrier(0);
    }
#pragma unroll
    for (int mt = 0; mt < 2; ++mt)
#pragma unroll
      for (int v = 0; v < 4; ++v) {
        const int b = w * 32 + mt * 16 + fg * 4 + v;
        float pi = acc[mt][0][v] + bias_reg[0];
        float pf = acc[mt][1][v] + bias_reg[1];
        float pg = acc[mt][2][v] + bias_reg[2];
        float po = acc[mt][3][v] + bias_reg[3];
        if (PHASE == 2) {
          pi += b2f(z_lds[b * 72 + 0 * 16 + fc]);
          pf += b2f(z_lds[b * 72 + 1 * 16 + fc]);
          pg += b2f(z_lds[b * 72 + 2 * 16 + fc]);
          po += b2f(z_lds[b * 72 + 3 * 16 + fc]);
        }
        const float c = sigm(pf) * c_reg[mt * 4 + v] + sigm(pi) * tanh_(pg);
        c_reg[mt * 4 + v] = c;
        hout[fc * 72 + b] = f2b(sigm(po) * tanh_(c));
      }
    asm volatile("s_waitcnt lgkmcnt(0)" ::: "memory");
    __builtin_amdgcn_sched_barrier(0);
    // ---- coalesced writeback to hT (intra-wave transpose) ----
    {
      const int bb = tid >> 1, hh = tid & 1;
      s8v o;
#pragma unroll
      for (int e = 0; e < 8; ++e) o[e] = (short)hout[(hh * 8 + e) * 72 + bb];
      stg_b128_sc(hb + (size_t)(s & 1) * (64 * 512) +
                  (size_t)(((j0 >> 3) + hh) * 64 + bb) * 8, o);
      if (PHASE == 1) {
        *(s8v*)(yout + ((size_t)(bb * 512 + t)) * 1024 + dir * 512 + j0 + hh * 8) = o;
      } else if (s == 511) {
        *(s8v*)(yout + (size_t)bb * 1024 + dir * 512 + j0 + hh * 8) = o;
      }
    }
    if (PHASE == 2 && s == s1 - 1 && s1 < 512) {
#pragma unroll
      for (int mt = 0; mt < 2; ++mt)
#pragma unroll
        for (int v = 0; v < 4; ++v)
          cg[(size_t)dir * 32768 + (size_t)(w * 32 + mt * 16 + fg * 4 + v) * 512 + j0 + fc] =
            c_reg[mt * 4 + v];
    }
    // ---- per-wave drain + publish (vmcnt is per-wave: covers all 64 lanes) --
    asm volatile("s_waitcnt vmcnt(0)" ::: "memory");
    __builtin_amdgcn_sched_barrier(0);
    if (lane == 0) AT_STORE_RLX(&flg[wg * 2 + w], s + 1);
  }
}

// ---------------------------------------------------------------------------
// z2 chunk GEMM: (64*CT) x 2048, K=1024, 128x128 tiles
// ---------------------------------------------------------------------------
__global__ void __launch_bounds__(256)
k_zgemm(const unsigned short* __restrict__ A, const unsigned short* __restrict__ Wxt,
        unsigned short* __restrict__ Cf, unsigned short* __restrict__ Cb,
        int tb0, int tb1, int CT)
{
  __shared__ unsigned short As[128 * 64];
  __shared__ unsigned short Bs[128 * 64];
  const int tid = threadIdx.x;
  const int lane = tid & 63;
  const int w = tid >> 6;
  const int wm = w >> 1, wn = w & 1;
  const int bx = blockIdx.x, by = blockIdx.y, dz = blockIdx.z;
  const unsigned short* Bmat = Wxt + (size_t)dz * 2048 * 1024;
  unsigned short* C = dz ? Cb : Cf;
  const int tb = dz ? tb1 : tb0;
  const int fc = lane & 15, fk = (lane >> 4) << 3;

  f32x4 acc[4][4];
#pragma unroll
  for (int mt = 0; mt < 4; ++mt)
#pragma unroll
    for (int nt = 0; nt < 4; ++nt) acc[mt][nt] = (f32x4){0.f, 0.f, 0.f, 0.f};

  for (int kt = 0; kt < 16; ++kt) {
    __syncthreads();
#pragma unroll
    for (int i = 0; i < 4; ++i) {
      const int c = i * 256 + tid;
      const int row = c >> 3, kb = c & 7;
      const int m = by * 128 + row;
      const int b = m / CT, lt = m - b * CT;
      s8v v = *(const s8v*)(A + ((size_t)b * 512 + tb + lt) * 1024 + kt * 64 + kb * 8);
      *(s8v*)((char*)As + row * 128 + ((kb * 16) ^ ((row & 7) << 4))) = v;
    }
#pragma unroll
    for (int i = 0; i < 4; ++i) {
      const int c = i * 256 + tid;
      const int n = c >> 3, kb = c & 7;
      s8v v = *(const s8v*)(Bmat + (size_t)(bx * 128 + n) * 1024 + kt * 64 + kb * 8);
      *(s8v*)((char*)Bs + n * 128 + ((kb * 16) ^ ((n & 7) << 4))) = v;
    }
    __syncthreads();
#pragma unroll
    for (int kk = 0; kk < 2; ++kk) {
      const int k2 = (kk * 32 + fk) * 2;
      s8v a[4], bfr[4];
#pragma unroll
      for (int mt = 0; mt < 4; ++mt) {
        const int row = wm * 64 + mt * 16 + fc;
        a[mt] = *(const s8v*)((char*)As + row * 128 + (k2 ^ ((row & 7) << 4)));
      }
#pragma unroll
      for (int nt = 0; nt < 4; ++nt) {
        const int n = wn * 64 + nt * 16 + fc;
        bfr[nt] = *(const s8v*)((char*)Bs + n * 128 + (k2 ^ ((n & 7) << 4)));
      }
#pragma unroll
      for (int mt = 0; mt < 4; ++mt)
#pragma unroll
        for (int nt = 0; nt < 4; ++nt)
          acc[mt][nt] = __builtin_amdgcn_mfma_f32_16x16x32_bf16(a[mt], bfr[nt], acc[mt][nt], 0, 0, 0);
    }
  }
  const int r0 = (lane >> 4) << 2;
#pragma unroll
  for (int mt = 0; mt < 4; ++mt)
#pragma unroll
    for (int nt = 0; nt < 4; ++nt) {
      const size_t rowg = (size_t)(by * 128 + wm * 64 + mt * 16 + r0);
      const int colg = bx * 128 + wn * 64 + nt * 16 + fc;
#pragma unroll
      for (int r = 0; r < 4; ++r)
        C[(rowg + r) * 2048 + colg] = f2b(acc[mt][nt][r]);
    }
}

// ---------------------------------------------------------------------------
// Head part 1: S=1 attention collapses to v-proj -> Wo -> query
// ---------------------------------------------------------------------------
__global__ void __launch_bounds__(256)
k_head1(const unsigned short* __restrict__ x2,
        const float* __restrict__ Wv, const float* __restrict__ bv,
        const float* __restrict__ Wo, const float* __restrict__ bo,
        const float* __restrict__ mqW, const float* __restrict__ mqb,
        float* __restrict__ query)
{
  __shared__ float xs[1024], ys[512], x3[1024];
  __shared__ float part[4][64];
  const int b = blockIdx.x, tid = threadIdx.x;
  for (int i = tid; i < 1024; i += 256) xs[i] = b2f(x2[(size_t)b * 1024 + i]);
  __syncthreads();
  {
    const int o = tid * 2;
    float a0 = 0.f, a1 = 0.f;
#pragma unroll 8
    for (int e = 0; e < 1024; ++e) {
      const float xv = xs[e];
      a0 += xv * Wv[(size_t)e * 512 + o];
      a1 += xv * Wv[(size_t)e * 512 + o + 1];
    }
    ys[o] = a0 + bv[o];
    ys[o + 1] = a1 + bv[o + 1];
  }
  __syncthreads();
  {
    const int e0 = tid * 4;
    float a0 = 0.f, a1 = 0.f, a2 = 0.f, a3 = 0.f;
#pragma unroll 8
    for (int h = 0; h < 512; ++h) {
      const float yv = ys[h];
      a0 += yv * Wo[(size_t)h * 1024 + e0];
      a1 += yv * Wo[(size_t)h * 1024 + e0 + 1];
      a2 += yv * Wo[(size_t)h * 1024 + e0 + 2];
      a3 += yv * Wo[(size_t)h * 1024 + e0 + 3];
    }
    x3[e0] = a0 + bo[e0];
    x3[e0 + 1] = a1 + bo[e0 + 1];
    x3[e0 + 2] = a2 + bo[e0 + 2];
    x3[e0 + 3] = a3 + bo[e0 + 3];
  }
  __syncthreads();
  {
    const int o = tid & 63, kc = tid >> 6;
    float a = 0.f;
#pragma unroll 8
    for (int e = kc * 256; e < kc * 256 + 256; ++e) a += x3[e] * mqW[(size_t)e * 64 + o];
    part[kc][o] = a;
  }
  __syncthreads();
  if (tid < 64)
    query[b * 64 + tid] = part[0][tid] + part[1][tid] + part[2][tid] + part[3][tid] + mqb[tid];
}

// ---------------------------------------------------------------------------
// Head part 2: memory retrievals + MLP + sigmoid (f32 output)
// ---------------------------------------------------------------------------
__device__ void bank_topk(const float* __restrict__ K, const float* __restrict__ V,
                          int n, const float* __restrict__ W, const float* __restrict__ inn,
                          float qinv, const float* q, float* sims, float* red, int* redi,
                          float* acc64, int tid)
{
  for (int i = tid; i < n; i += 256) {
    float s = 0.f;
#pragma unroll 16
    for (int d = 0; d < 64; ++d) s += q[d] * K[(size_t)i * 64 + d];
    s *= qinv * inn[i];
    if (W) s *= W[i];
    sims[i] = s;
  }
  __syncthreads();
  for (int it = 0; it < 5; ++it) {
    float bv = -1e30f; int bi = 1 << 30;
    for (int i = tid; i < n; i += 256) {
      const float v = sims[i];
      if (v > bv) { bv = v; bi = i; }
    }
    red[tid] = bv; redi[tid] = bi;
    __syncthreads();
    for (int st = 128; st >= 1; st >>= 1) {
      if (tid < st) {
        const float v = red[tid + st]; const int ix = redi[tid + st];
        if (v > red[tid] || (v == red[tid] && ix < redi[tid])) { red[tid] = v; redi[tid] = ix; }
      }
      __syncthreads();
    }
    const int sel = redi[0];
    if (tid < 64) acc64[tid] += V[(size_t)sel * 64 + tid];
    if (tid == 0) sims[sel] = -1e30f;
    __syncthreads();
  }
}

__global__ void __launch_bounds__(256)
k_head2(const float* __restrict__ query,
        const float* extK, const float* extV,
        const float* formE, const float* concK, const float* concV,
        const float* stM, const float* ltM, const float* ltW,
        const float* infM, const float* infW,
        const float* __restrict__ inn,
        const float* rsW, const float* rsb,
        const float* gma, const float* bta,
        const float* mea, const float* vr,
        const float* outW, const float* outb,
        const float* finW, const float* finb,
        float* __restrict__ out)
{
  __shared__ float q[64];
  __shared__ float acc64[64];
  __shared__ float sims[10000];
  __shared__ float red[256];
  __shared__ int redi[256];
  __shared__ float r1[512];
  __shared__ float o2[128];

  const int b = blockIdx.x, tid = threadIdx.x;
  if (tid < 64) q[tid] = query[b * 64 + tid];
  __syncthreads();
  red[tid] = (tid < 64) ? q[tid] * q[tid] : 0.f;
  __syncthreads();
  for (int st = 128; st >= 1; st >>= 1) { if (tid < st) red[tid] += red[tid + st]; __syncthreads(); }
  const float qinv = 1.f / (sqrtf(red[0]) + 1e-6f);
  __syncthreads();

  if (tid < 100) {
    float s = 0.f;
#pragma unroll 16
    for (int d = 0; d < 64; ++d) s += q[d] * extK[(size_t)tid * 64 + d];
    sims[tid] = s;
  }
  __syncthreads();
  red[tid] = (tid < 100) ? sims[tid] : -1e30f;
  __syncthreads();
  for (int st = 128; st >= 1; st >>= 1) { if (tid < st && red[tid + st] > red[tid]) red[tid] = red[tid + st]; __syncthreads(); }
  const float mx = red[0];
  __syncthreads();
  red[tid] = (tid < 100) ? __expf(sims[tid] - mx) : 0.f;
  __syncthreads();
  for (int st = 128; st >= 1; st >>= 1) { if (tid < st) red[tid] += red[tid + st]; __syncthreads(); }
  const float Z = red[0];
  __syncthreads();
  if (tid < 100) sims[tid] = __expf(sims[tid] - mx) / Z;
  __syncthreads();
  if (tid < 64) {
    float a = 0.f;
    for (int i = 0; i < 100; ++i) a += sims[i] * extV[(size_t)i * 64 + tid];
    acc64[tid] = a;
  }
  __syncthreads();

  bank_topk(formE, formE, 1000,  nullptr, inn + 0,     qinv, q, sims, red, redi, acc64, tid);
  bank_topk(concK, concV, 1000,  nullptr, inn + 1000,  qinv, q, sims, red, redi, acc64, tid);
  bank_topk(stM,   stM,   100,   nullptr, inn + 2000,  qinv, q, sims, red, redi, acc64, tid);
  bank_topk(ltM,   ltM,   10000, ltW,     inn + 2100,  qinv, q, sims, red, redi, acc64, tid);
  bank_topk(infM,  infM,  500,   infW,    inn + 12100, qinv, q, sims, red, redi, acc64, tid);

  if (tid < 64) acc64[tid] *= (1.f / 26.f);
  __syncthreads();

  {
    const int o = tid * 2;
    float a0 = 0.f, a1 = 0.f;
#pragma unroll 16
    for (int d = 0; d < 64; ++d) {
      const float xv = acc64[d];
      a0 += xv * rsW[(size_t)d * 512 + o];
      a1 += xv * rsW[(size_t)d * 512 + o + 1];
    }
    a0 = fmaxf(a0 + rsb[o], 0.f);
    a1 = fmaxf(a1 + rsb[o + 1], 0.f);
    r1[o]     = (a0 - mea[o])     / sqrtf(vr[o]     + 1e-3f) * gma[o]     + bta[o];
    r1[o + 1] = (a1 - mea[o + 1]) / sqrtf(vr[o + 1] + 1e-3f) * gma[o + 1] + bta[o + 1];
  }
  __syncthreads();
  if (tid < 128) {
    float a = 0.f;
#pragma unroll 8
    for (int j = 0; j < 512; ++j) a += r1[j] * outW[(size_t)j * 128 + tid];
    o2[tid] = a + outb[tid];
  }
  __syncthreads();
  red[tid] = (tid < 128) ? o2[tid] * finW[tid] : 0.f;
  __syncthreads();
  for (int st = 128; st >= 1; st >>= 1) { if (tid < st) red[tid] += red[tid + st]; __syncthreads(); }
  if (tid == 0) out[b] = sigm(red[0] + finb[0]);
}

// Diagnostic: encode ws MiB as float
__global__ void k_diag(float* out, int n, float val) {
  const int i = blockIdx.x * 64 + threadIdx.x;
  if (i < n) out[i] = val;
}

// ---------------------------------------------------------------------------
// Launch
// ---------------------------------------------------------------------------
extern "C" void kernel_launch(void* const* d_in, const int* in_sizes, int n_in,
                              void* d_out, int out_size, void* d_ws, size_t ws_size,
                              hipStream_t stream)
{
  (void)in_sizes; (void)n_in;
  const int*   tokens = (const int*)d_in[0];
  const float* emb    = (const float*)d_in[1];
  const float* l1fWx  = (const float*)d_in[2];
  const float* l1fWh  = (const float*)d_in[3];
  const float* l1fb   = (const float*)d_in[4];
  const float* l1bWx  = (const float*)d_in[5];
  const float* l1bWh  = (const float*)d_in[6];
  const float* l1bb   = (const float*)d_in[7];
  const float* l2fWx  = (const float*)d_in[8];
  const float* l2fWh  = (const float*)d_in[9];
  const float* l2fb   = (const float*)d_in[10];
  const float* l2bWx  = (const float*)d_in[11];
  const float* l2bWh  = (const float*)d_in[12];
  const float* l2bb   = (const float*)d_in[13];
  const float* Wv     = (const float*)d_in[18];
  const float* bv     = (const float*)d_in[19];
  const float* Wo     = (const float*)d_in[20];
  const float* bo     = (const float*)d_in[21];
  const float* mqW    = (const float*)d_in[22];
  const float* mqb    = (const float*)d_in[23];
  const float* extK   = (const float*)d_in[24];
  const float* extV   = (const float*)d_in[25];
  const float* formE  = (const float*)d_in[26];
  const float* concK  = (const float*)d_in[27];
  const float* concV  = (const float*)d_in[28];
  const float* stM    = (const float*)d_in[29];
  const float* ltM    = (const float*)d_in[30];
  const float* ltW    = (const float*)d_in[31];
  const float* infM   = (const float*)d_in[32];
  const float* infW   = (const float*)d_in[33];
  const float* rsW    = (const float*)d_in[34];
  const float* rsb    = (const float*)d_in[35];
  const float* gma    = (const float*)d_in[36];
  const float* bta    = (const float*)d_in[37];
  const float* mea    = (const float*)d_in[38];
  const float* vr     = (const float*)d_in[39];
  const float* outW   = (const float*)d_in[40];
  const float* outb   = (const float*)d_in[41];
  const float* finW   = (const float*)d_in[42];
  const float* finb   = (const float*)d_in[43];

  float* outp = (float*)d_out;
  char* ws = (char*)d_ws;

  size_t off = 0;
  auto take = [&](size_t sz) { size_t o = off; off += (sz + 255) & ~(size_t)255; return o; };
  const size_t o_x1    = take((size_t)64 * 512 * 64 * 2);
  const size_t o_y1    = take((size_t)64 * 512 * 1024 * 2);
  const size_t o_wxt   = take((size_t)2 * 2048 * 1024 * 2);
  const size_t o_wht1  = take((size_t)2 * 2048 * 512 * 2);
  const size_t o_wht2  = take((size_t)2 * 2048 * 512 * 2);
  const size_t o_h1    = take((size_t)2 * 2 * 64 * 512 * 2);
  const size_t o_h2    = take((size_t)2 * 2 * 64 * 512 * 2);
  const size_t o_cg    = take((size_t)2 * 64 * 512 * 4);
  const size_t o_x2    = take((size_t)64 * 1024 * 2);
  const size_t o_query = take((size_t)64 * 64 * 4);
  const size_t o_norms = take((size_t)12600 * 4);
  const size_t o_flags = take(1024);
  const size_t base = off;

  int CT = 0;
  const int cts[6] = {512, 256, 128, 64, 32, 16};
  for (int i = 0; i < 6; ++i) {
    const size_t need = base + (size_t)cts[i] * 524288 + 256;
    if (need <= ws_size) { CT = cts[i]; break; }
  }
  if (CT == 0) {
    k_diag<<<1, 64, 0, stream>>>(outp, out_size, (float)(ws_size >> 20));
    return;
  }
  const size_t o_zc = take((size_t)CT * 524288);

  unsigned short* x1t  = (unsigned short*)(ws + o_x1);
  unsigned short* y1   = (unsigned short*)(ws + o_y1);
  unsigned short* wxt  = (unsigned short*)(ws + o_wxt);
  unsigned short* wht1 = (unsigned short*)(ws + o_wht1);
  unsigned short* wht2 = (unsigned short*)(ws + o_wht2);
  unsigned short* h1   = (unsigned short*)(ws + o_h1);
  unsigned short* h2   = (unsigned short*)(ws + o_h2);
  float*          cg   = (float*)(ws + o_cg);
  unsigned short* x2   = (unsigned short*)(ws + o_x2);
  float*          qry  = (float*)(ws + o_query);
  float*          nrm  = (float*)(ws + o_norms);
  int*            flags = (int*)(ws + o_flags);
  unsigned short* zcf  = (unsigned short*)(ws + o_zc);
  unsigned short* zcb  = zcf + (size_t)64 * CT * 2048;

  hipMemsetAsync(flags, 0, 1024, stream);
  k_embed<<<1024, 256, 0, stream>>>(tokens, emb, x1t);
  k_norms<<<50, 256, 0, stream>>>(formE, concK, stM, ltM, infM, nrm);
  k_tr<<<dim3(8, 32, 2), 256, 0, stream>>>(l1fWh, l1bWh, wht1, 512, 2048);
  k_tr<<<dim3(8, 32, 2), 256, 0, stream>>>(l2fWh, l2bWh, wht2, 512, 2048);
  k_tr<<<dim3(16, 32, 2), 256, 0, stream>>>(l2fWx, l2bWx, wxt, 1024, 2048);

  k_lstm<1><<<64, 128, 0, stream>>>(x1t, nullptr, nullptr, wht1, l1fWx, l1bWx,
                                    l1fb, l1bb, h1, y1, flags, nullptr, 0, 512, 512);

  const int nC = 512 / CT;
  for (int c = 0; c < nC; ++c) {
    const int s0 = c * CT, s1 = s0 + CT;
    k_zgemm<<<dim3(16, (64 * CT) / 128, 2), 256, 0, stream>>>(
        y1, wxt, zcf, zcb, s0, 512 - s1, CT);
    k_lstm<2><<<64, 128, 0, stream>>>(nullptr, zcf, zcb, wht2, nullptr, nullptr,
                                      l2fb, l2bb, h2, x2, flags + 128, cg, s0, s1, CT);
  }

  k_head1<<<64, 256, 0, stream>>>(x2, Wv, bv, Wo, bo, mqW, mqb, qry);
  k_head2<<<64, 256, 0, stream>>>(qry, extK, extV, formE, concK, concV, stM, ltM, ltW,
                                  infM, infW, nrm, rsW, rsb, gma, bta, mea, vr,
                                  outW, outb, finW, finb, outp);
}